// Round 5
// baseline (2838.700 us; speedup 1.0000x reference)
//
#include <hip/hip_runtime.h>
#include <math.h>

#define N_NODES 50000
#define F_IN 128
#define E_RAW 800000
#define E_TOT (E_RAW + N_NODES)   // self-loops appended
#define NEG_SLOPE 0.2f

// ---------------------------------------------------------------------------
// Kernel 1: LDS-tiled fused GEMM  X[N,128] @ [Wl1|Wr1|Wlin1] -> XL, XR, LIN
// Block = 256 threads, output tile 128 rows x 64 cols, K chunked by 16,
// double-buffered LDS, reg-staged (issue chunk k+1 loads before compute k).
// Per-thread: 8 rows x 4 cols register tile.
// ---------------------------------------------------------------------------
#define TR 128   // tile rows
#define TC 64    // tile cols
#define KB 16    // k chunk
#define XPAD 17  // padded stride for X tile (kills 4-way bank conflict)

__global__ __launch_bounds__(256) void gemm1_kernel(
    const float* __restrict__ x,
    const float* __restrict__ Wl, const float* __restrict__ Wr,
    const float* __restrict__ Wlin,
    float* __restrict__ XL, float* __restrict__ XR, float* __restrict__ LIN)
{
    __shared__ float XS[2][TR][XPAD];   // [buf][row][k]  17*4B stride
    __shared__ float WS[2][KB][TC];     // [buf][k][col]

    const int t  = threadIdx.x;
    const int tx = t & 15;              // col group: cols tx*4..tx*4+3
    const int ty = t >> 4;              // row group: rows ty*8..ty*8+7

    const int r0   = blockIdx.x * TR;
    const int half = blockIdx.y & 1;    // which 64-col half of the 128-col W
    const int mat  = blockIdx.y >> 1;   // 0=Wl 1=Wr 2=Wlin
    const int cs0  = half * 64;

    const float* Wsel = (mat == 0) ? Wl : (mat == 1) ? Wr : Wlin;
    float*       Osel = (mat == 0) ? XL : (mat == 1) ? XR : LIN;

    // staging indices
    // X: 512 float4 slots per chunk (128 rows x 4 float4); thread does slots t, t+256
    const int xs0_row = (t)        >> 2, xs0_kj = (t)        & 3;
    const int xs1_row = (t + 256)  >> 2, xs1_kj = (t + 256)  & 3;
    // W: 256 float4 slots (16 k x 16 col-groups); thread does slot t
    const int wk = t >> 4, wc = t & 15;

    float4 xa0, xa1, wa;

    #define LOAD_CHUNK(k0)                                                     \
    {                                                                          \
        const int gr0 = r0 + xs0_row, gr1 = r0 + xs1_row;                      \
        xa0 = (gr0 < N_NODES)                                                  \
            ? *(const float4*)(x + (size_t)gr0 * 128 + (k0) + xs0_kj * 4)      \
            : make_float4(0.f, 0.f, 0.f, 0.f);                                 \
        xa1 = (gr1 < N_NODES)                                                  \
            ? *(const float4*)(x + (size_t)gr1 * 128 + (k0) + xs1_kj * 4)      \
            : make_float4(0.f, 0.f, 0.f, 0.f);                                 \
        wa  = *(const float4*)(Wsel + (size_t)((k0) + wk) * 128 + cs0 + wc*4); \
    }

    #define WRITE_CHUNK(buf)                                                   \
    {                                                                          \
        XS[buf][xs0_row][xs0_kj*4+0] = xa0.x;                                  \
        XS[buf][xs0_row][xs0_kj*4+1] = xa0.y;                                  \
        XS[buf][xs0_row][xs0_kj*4+2] = xa0.z;                                  \
        XS[buf][xs0_row][xs0_kj*4+3] = xa0.w;                                  \
        XS[buf][xs1_row][xs1_kj*4+0] = xa1.x;                                  \
        XS[buf][xs1_row][xs1_kj*4+1] = xa1.y;                                  \
        XS[buf][xs1_row][xs1_kj*4+2] = xa1.z;                                  \
        XS[buf][xs1_row][xs1_kj*4+3] = xa1.w;                                  \
        *(float4*)&WS[buf][wk][wc*4] = wa;                                     \
    }

    float acc[8][4];
    #pragma unroll
    for (int r = 0; r < 8; ++r)
        #pragma unroll
        for (int c = 0; c < 4; ++c) acc[r][c] = 0.f;

    LOAD_CHUNK(0);
    WRITE_CHUNK(0);
    __syncthreads();

    #pragma unroll
    for (int ch = 0; ch < 8; ++ch) {
        const int buf = ch & 1;
        if (ch < 7) LOAD_CHUNK((ch + 1) * KB);   // issue next-chunk loads early

        #pragma unroll
        for (int k = 0; k < KB; ++k) {
            const float4 wv = *(const float4*)&WS[buf][k][tx * 4];
            float xv[8];
            #pragma unroll
            for (int r = 0; r < 8; ++r) xv[r] = XS[buf][ty * 8 + r][k];
            #pragma unroll
            for (int r = 0; r < 8; ++r) {
                acc[r][0] = fmaf(xv[r], wv.x, acc[r][0]);
                acc[r][1] = fmaf(xv[r], wv.y, acc[r][1]);
                acc[r][2] = fmaf(xv[r], wv.z, acc[r][2]);
                acc[r][3] = fmaf(xv[r], wv.w, acc[r][3]);
            }
        }
        __syncthreads();
        if (ch < 7) {
            WRITE_CHUNK(buf ^ 1);
            __syncthreads();
        }
    }

    #pragma unroll
    for (int r = 0; r < 8; ++r) {
        const int grow = r0 + ty * 8 + r;
        if (grow < N_NODES) {
            float4 o = make_float4(acc[r][0], acc[r][1], acc[r][2], acc[r][3]);
            *(float4*)(Osel + (size_t)grow * 128 + cs0 + tx * 4) = o;
        }
    }
    #undef LOAD_CHUNK
    #undef WRITE_CHUNK
}

// ---------------------------------------------------------------------------
// CSR build: histogram of dst, exclusive scan, scatter src ids
// ---------------------------------------------------------------------------
__global__ __launch_bounds__(256) void hist_kernel(
    const int* __restrict__ eidx, int* __restrict__ counts)
{
    const int e = blockIdx.x * blockDim.x + threadIdx.x;
    if (e >= E_TOT) return;
    const int d = (e < E_RAW) ? eidx[E_RAW + e] : e - E_RAW;
    atomicAdd(&counts[d], 1);
}

// single-block scan: counts[50000] -> exclusive rowptr[50001], cursor copy
__global__ __launch_bounds__(1024) void scan_kernel(
    const int* __restrict__ counts, int* __restrict__ rowptr, int* __restrict__ cursor)
{
    __shared__ int wsum[16];
    __shared__ int carry_s;
    const int tid = threadIdx.x, lane = tid & 63, wv = tid >> 6;
    if (tid == 0) carry_s = 0;
    __syncthreads();

    for (int base = 0; base < N_NODES; base += 1024) {
        const int i = base + tid;
        const int orig = (i < N_NODES) ? counts[i] : 0;
        int v = orig;
        #pragma unroll
        for (int off = 1; off < 64; off <<= 1) {
            int t = __shfl_up(v, off);
            if (lane >= off) v += t;
        }
        if (lane == 63) wsum[wv] = v;
        __syncthreads();
        if (wv == 0) {
            int s = (lane < 16) ? wsum[lane] : 0;
            #pragma unroll
            for (int off = 1; off < 16; off <<= 1) {
                int t = __shfl_up(s, off);
                if (lane >= off) s += t;
            }
            if (lane < 16) wsum[lane] = s;
        }
        __syncthreads();
        const int carry = carry_s;
        const int woff  = (wv == 0) ? 0 : wsum[wv - 1];
        const int excl  = carry + woff + v - orig;
        if (i < N_NODES) { rowptr[i] = excl; cursor[i] = excl; }
        __syncthreads();
        if (tid == 0) carry_s += wsum[15];
        __syncthreads();
    }
    if (threadIdx.x == 0) rowptr[N_NODES] = carry_s;
}

__global__ __launch_bounds__(256) void scatter_kernel(
    const int* __restrict__ eidx, int* __restrict__ cursor, int* __restrict__ csr_src)
{
    const int e = blockIdx.x * blockDim.x + threadIdx.x;
    if (e >= E_TOT) return;
    int s, d;
    if (e < E_RAW) { s = eidx[e]; d = eidx[E_RAW + e]; }
    else           { s = d = e - E_RAW; }
    const int pos = atomicAdd(&cursor[d], 1);
    csr_src[pos] = s;
}

// ---------------------------------------------------------------------------
// Fused layer-1 GAT: one wave per dst node. score+softmax+aggregate+bias+skip+relu
// ---------------------------------------------------------------------------
__global__ __launch_bounds__(256) void fused1_kernel(
    const float* __restrict__ xl, const float* __restrict__ xr,
    const float* __restrict__ lin,
    const int* __restrict__ rowptr, const int* __restrict__ csr_src,
    const float* __restrict__ att, const float* __restrict__ b1,
    const float* __restrict__ blin1,
    float* __restrict__ h)
{
    const int gid  = blockIdx.x * blockDim.x + threadIdx.x;
    const int d    = gid >> 6;
    const int lane = gid & 63;
    if (d >= N_NODES) return;

    const int r0 = rowptr[d], r1 = rowptr[d + 1];
    const float2 xrd = ((const float2*)(xr + (size_t)d * 128))[lane];
    const float2 at  = ((const float2*)att)[lane];

    float num0 = 0.f, num1 = 0.f, den = 0.f;
    for (int j = r0; j < r1; ++j) {
        const int s = csr_src[j];
        const float2 a = ((const float2*)(xl + (size_t)s * 128))[lane];
        float m0 = a.x + xrd.x, m1 = a.y + xrd.y;
        m0 = m0 > 0.f ? m0 : NEG_SLOPE * m0;
        m1 = m1 > 0.f ? m1 : NEG_SLOPE * m1;
        float v = m0 * at.x + m1 * at.y;
        #pragma unroll
        for (int off = 32; off > 0; off >>= 1) v += __shfl_xor(v, off);
        const float ex = __expf(v);
        den += ex;
        num0 = fmaf(ex, a.x, num0);
        num1 = fmaf(ex, a.y, num1);
    }
    const float inv = 1.f / den;
    const float2 lv = ((const float2*)(lin   + (size_t)d * 128))[lane];
    const float2 bb = ((const float2*)b1)[lane];
    const float2 bl = ((const float2*)blin1)[lane];
    float h0 = fmaf(num0, inv, bb.x) + lv.x + bl.x;
    float h1 = fmaf(num1, inv, bb.y) + lv.y + bl.y;
    h0 = h0 > 0.f ? h0 : 0.f;
    h1 = h1 > 0.f ? h1 : 0.f;
    ((float2*)(h + (size_t)d * 128))[lane] = make_float2(h0, h1);
}

// ---------------------------------------------------------------------------
// Layer-2 small GEMM: one wave per row -> XL2, XR2, LIN2 (each [N,2])
// ---------------------------------------------------------------------------
__global__ __launch_bounds__(256) void gemm2_kernel(
    const float* __restrict__ h,
    const float* __restrict__ Wl2, const float* __restrict__ Wr2,
    const float* __restrict__ Wlin2,
    float* __restrict__ XL2, float* __restrict__ XR2, float* __restrict__ LIN2)
{
    const int gid  = blockIdx.x * blockDim.x + threadIdx.x;
    const int row  = gid >> 6;
    const int lane = gid & 63;
    if (row >= N_NODES) return;

    const float2 hv = ((const float2*)(h + (size_t)row * 128))[lane];
    const int k0 = 2 * lane, k1 = 2 * lane + 1;

    float v[6];
    v[0] = hv.x * Wl2[k0*2+0]   + hv.y * Wl2[k1*2+0];
    v[1] = hv.x * Wl2[k0*2+1]   + hv.y * Wl2[k1*2+1];
    v[2] = hv.x * Wr2[k0*2+0]   + hv.y * Wr2[k1*2+0];
    v[3] = hv.x * Wr2[k0*2+1]   + hv.y * Wr2[k1*2+1];
    v[4] = hv.x * Wlin2[k0*2+0] + hv.y * Wlin2[k1*2+0];
    v[5] = hv.x * Wlin2[k0*2+1] + hv.y * Wlin2[k1*2+1];

    #pragma unroll
    for (int off = 32; off > 0; off >>= 1) {
        #pragma unroll
        for (int j = 0; j < 6; ++j) v[j] += __shfl_xor(v[j], off);
    }

    if (lane == 0) {
        XL2[row*2+0]  = v[0]; XL2[row*2+1]  = v[1];
        XR2[row*2+0]  = v[2]; XR2[row*2+1]  = v[3];
        LIN2[row*2+0] = v[4]; LIN2[row*2+1] = v[5];
    }
}

// ---------------------------------------------------------------------------
// Fused layer-2 GAT + bias + skip + log_softmax: one thread per node.
// ---------------------------------------------------------------------------
__global__ __launch_bounds__(256) void fused2_kernel(
    const float* __restrict__ XL2, const float* __restrict__ XR2,
    const float* __restrict__ LIN2,
    const int* __restrict__ rowptr, const int* __restrict__ csr_src,
    const float* __restrict__ att2, const float* __restrict__ b2,
    const float* __restrict__ blin2,
    float* __restrict__ out)
{
    const int d = blockIdx.x * blockDim.x + threadIdx.x;
    if (d >= N_NODES) return;

    const int r0 = rowptr[d], r1 = rowptr[d + 1];
    const float xr0 = XR2[d*2+0], xr1 = XR2[d*2+1];
    const float a0 = att2[0], a1 = att2[1];

    float num0 = 0.f, num1 = 0.f, den = 0.f;
    for (int j = r0; j < r1; ++j) {
        const int s = csr_src[j];
        const float l0 = XL2[s*2+0], l1 = XL2[s*2+1];
        float m0 = l0 + xr0, m1 = l1 + xr1;
        m0 = m0 > 0.f ? m0 : NEG_SLOPE * m0;
        m1 = m1 > 0.f ? m1 : NEG_SLOPE * m1;
        const float ex = __expf(m0 * a0 + m1 * a1);
        den += ex;
        num0 = fmaf(ex, l0, num0);
        num1 = fmaf(ex, l1, num1);
    }
    const float inv = 1.f / den;
    const float o0 = num0 * inv + b2[0] + LIN2[d*2+0] + blin2[0];
    const float o1 = num1 * inv + b2[1] + LIN2[d*2+1] + blin2[1];
    const float mx  = fmaxf(o0, o1);
    const float lse = mx + logf(__expf(o0 - mx) + __expf(o1 - mx));
    out[d*2+0] = o0 - lse;
    out[d*2+1] = o1 - lse;
}

// ---------------------------------------------------------------------------
// copy edge_index (int32) -> d_out tail as float32
// ---------------------------------------------------------------------------
__global__ __launch_bounds__(256) void copy_eidx_kernel(
    const int* __restrict__ eidx, float* __restrict__ out)
{
    const int i = blockIdx.x * blockDim.x + threadIdx.x;
    if (i >= 2 * E_RAW) return;
    out[i] = (float)eidx[i];
}

// ---------------------------------------------------------------------------
extern "C" void kernel_launch(void* const* d_in, const int* in_sizes, int n_in,
                              void* d_out, int out_size, void* d_ws, size_t ws_size,
                              hipStream_t stream)
{
    const float* x      = (const float*)d_in[0];
    const int*   eidx   = (const int*)  d_in[1];
    const float* Wl1    = (const float*)d_in[2];
    const float* Wr1    = (const float*)d_in[3];
    const float* att1   = (const float*)d_in[4];
    const float* b1     = (const float*)d_in[5];
    const float* Wlin1  = (const float*)d_in[6];
    const float* blin1  = (const float*)d_in[7];
    const float* Wl2    = (const float*)d_in[8];
    const float* Wr2    = (const float*)d_in[9];
    const float* att2   = (const float*)d_in[10];
    const float* b2     = (const float*)d_in[11];
    const float* Wlin2  = (const float*)d_in[12];
    const float* blin2  = (const float*)d_in[13];

    float* out = (float*)d_out;

    // workspace layout (4-byte elements)
    float* ws     = (float*)d_ws;
    float* XL     = ws;                        // [N,128]
    float* XR     = ws + 6400000;              // [N,128]  (fused1 writes H in-place)
    float* LIN    = ws + 12800000;             // [N,128]  (reused for layer-2 vecs)
    int*   counts = (int*)(ws + 19200000);     // [N]  (also scatter cursor)
    int*   rowptr = counts + 50000;            // [N+1]
    int*   csr    = rowptr + 50001;            // [E_TOT]
    float* H      = XR;
    float* XL2    = LIN;                       // [N,2] — LIN data dead after fused1
    float* XR2    = LIN + 100000;
    float* LIN2   = LIN + 200000;

    // --- Layer-1 GEMM (LDS-tiled) ---
    {
        dim3 grid((N_NODES + TR - 1) / TR, 6);
        gemm1_kernel<<<grid, 256, 0, stream>>>(x, Wl1, Wr1, Wlin1, XL, XR, LIN);
    }

    // --- CSR build ---
    hipMemsetAsync(counts, 0, N_NODES * sizeof(int), stream);
    hist_kernel<<<(E_TOT + 255) / 256, 256, 0, stream>>>(eidx, counts);
    scan_kernel<<<1, 1024, 0, stream>>>(counts, rowptr, counts);
    scatter_kernel<<<(E_TOT + 255) / 256, 256, 0, stream>>>(eidx, counts, csr);

    // --- Fused layer-1 GAT (wave per node) ---
    {
        const int blocks = (N_NODES * 64 + 255) / 256;
        fused1_kernel<<<blocks, 256, 0, stream>>>(XL, XR, LIN, rowptr, csr,
                                                  att1, b1, blin1, H);
    }

    // --- Layer 2 ---
    {
        const int blocks = (N_NODES * 64 + 255) / 256;
        gemm2_kernel<<<blocks, 256, 0, stream>>>(H, Wl2, Wr2, Wlin2, XL2, XR2, LIN2);
    }
    {
        const int blocks = (N_NODES + 255) / 256;
        fused2_kernel<<<blocks, 256, 0, stream>>>(XL2, XR2, LIN2, rowptr, csr,
                                                  att2, b2, blin2, out);
    }
    {
        const int blocks = (2 * E_RAW + 255) / 256;
        copy_eidx_kernel<<<blocks, 256, 0, stream>>>(eidx, out + (size_t)N_NODES * 2);
    }
}

// Round 6
// 456.428 us; speedup vs baseline: 6.2194x; 6.2194x over previous
//
#include <hip/hip_runtime.h>
#include <math.h>

#define N_NODES 50000
#define F_IN 128
#define E_RAW 800000
#define E_TOT (E_RAW + N_NODES)   // self-loops appended
#define NEG_SLOPE 0.2f

// ---------------------------------------------------------------------------
// Kernel 1: LDS-tiled fused GEMM  X[N,128] @ [Wl1|Wr1|Wlin1] -> XL, XR, LIN
// Tile: 128 rows x 64 cols, K chunked by 32 (runtime loop, single LDS buffer —
// round-5 lesson: the fully-unrolled double-buffered version spilled to
// scratch, 256 VGPR + 5 GB HBM traffic).
// X staged TRANSPOSED [k][row] so compute reads are ds_read_b128.
// Per thread: 8 rows x 4 cols (32 acc VGPRs). launch_bounds(256,4) caps
// the allocator at 128 VGPR.
// ---------------------------------------------------------------------------
#define TRR 128      // tile rows
#define TCC 64       // tile cols
#define KBB 32       // k chunk
#define XTS 132      // XT row stride in floats (128 + 4 pad; 16B-aligned)

__global__ __launch_bounds__(256, 4) void gemm1_kernel(
    const float* __restrict__ x,
    const float* __restrict__ Wl, const float* __restrict__ Wr,
    const float* __restrict__ Wlin,
    float* __restrict__ XL, float* __restrict__ XR, float* __restrict__ LIN)
{
    __shared__ float XT[KBB][XTS];   // [k][row] transposed X tile, ~16.9 KB
    __shared__ float WS[KBB][TCC];   // [k][col] 8 KB

    const int t  = threadIdx.x;
    const int tx = t & 15;           // col group: cols tx*4 .. tx*4+3
    const int ty = t >> 4;           // row group: rows ty*8 .. ty*8+7
                                     // (wave = 4 ty groups spanning 32 rows -> bank-conflict-free b128)
    const int r0   = blockIdx.x * TRR;
    const int half = blockIdx.y & 1;
    const int mat  = blockIdx.y >> 1;     // 0=Wl 1=Wr 2=Wlin
    const int cs0  = half * 64;

    const float* Wsel = (mat == 0) ? Wl : (mat == 1) ? Wr : Wlin;
    float*       Osel = (mat == 0) ? XL : (mat == 1) ? XR : LIN;

    // X staging: thread covers (row = t>>3 + 32*i, k4 = t&7); 8 consecutive
    // threads read 8 consecutive float4 of one row -> coalesced.
    const int sx_k4  = t & 7;
    const int sx_row = t >> 3;

    float acc[8][4];
    #pragma unroll
    for (int r = 0; r < 8; ++r)
        #pragma unroll
        for (int c = 0; c < 4; ++c) acc[r][c] = 0.f;

    for (int kc = 0; kc < 128; kc += KBB) {
        // --- stage X chunk (transposed) ---
        #pragma unroll
        for (int i = 0; i < 4; ++i) {
            const int row = sx_row + i * 32;
            const int gr  = r0 + row;
            float4 v = (gr < N_NODES)
                ? *(const float4*)(x + (size_t)gr * 128 + kc + sx_k4 * 4)
                : make_float4(0.f, 0.f, 0.f, 0.f);
            XT[sx_k4 * 4 + 0][row] = v.x;
            XT[sx_k4 * 4 + 1][row] = v.y;
            XT[sx_k4 * 4 + 2][row] = v.z;
            XT[sx_k4 * 4 + 3][row] = v.w;
        }
        // --- stage W chunk ---
        #pragma unroll
        for (int i = 0; i < 2; ++i) {
            const int wk = (t >> 4) + i * 16;
            float4 wv = *(const float4*)(Wsel + (size_t)(kc + wk) * 128 + cs0 + tx * 4);
            *(float4*)&WS[wk][tx * 4] = wv;
        }
        __syncthreads();

        // --- compute: per k, 2x b128 X rows + 1x b128 W cols, 32 FMA ---
        #pragma unroll 8
        for (int k = 0; k < KBB; ++k) {
            const float4 xlo = *(const float4*)&XT[k][ty * 8];
            const float4 xhi = *(const float4*)&XT[k][ty * 8 + 4];
            const float4 wv  = *(const float4*)&WS[k][tx * 4];
            const float xs[8] = {xlo.x, xlo.y, xlo.z, xlo.w,
                                 xhi.x, xhi.y, xhi.z, xhi.w};
            #pragma unroll
            for (int r = 0; r < 8; ++r) {
                acc[r][0] = fmaf(xs[r], wv.x, acc[r][0]);
                acc[r][1] = fmaf(xs[r], wv.y, acc[r][1]);
                acc[r][2] = fmaf(xs[r], wv.z, acc[r][2]);
                acc[r][3] = fmaf(xs[r], wv.w, acc[r][3]);
            }
        }
        __syncthreads();
    }

    #pragma unroll
    for (int r = 0; r < 8; ++r) {
        const int grow = r0 + ty * 8 + r;
        if (grow < N_NODES) {
            float4 o = make_float4(acc[r][0], acc[r][1], acc[r][2], acc[r][3]);
            *(float4*)(Osel + (size_t)grow * 128 + cs0 + tx * 4) = o;
        }
    }
}

// ---------------------------------------------------------------------------
// CSR build: histogram of dst, exclusive scan, scatter src ids
// ---------------------------------------------------------------------------
__global__ __launch_bounds__(256) void hist_kernel(
    const int* __restrict__ eidx, int* __restrict__ counts)
{
    const int e = blockIdx.x * blockDim.x + threadIdx.x;
    if (e >= E_TOT) return;
    const int d = (e < E_RAW) ? eidx[E_RAW + e] : e - E_RAW;
    atomicAdd(&counts[d], 1);
}

// single-block scan: counts[50000] -> exclusive rowptr[50001], cursor copy
__global__ __launch_bounds__(1024) void scan_kernel(
    const int* __restrict__ counts, int* __restrict__ rowptr, int* __restrict__ cursor)
{
    __shared__ int wsum[16];
    __shared__ int carry_s;
    const int tid = threadIdx.x, lane = tid & 63, wv = tid >> 6;
    if (tid == 0) carry_s = 0;
    __syncthreads();

    for (int base = 0; base < N_NODES; base += 1024) {
        const int i = base + tid;
        const int orig = (i < N_NODES) ? counts[i] : 0;
        int v = orig;
        #pragma unroll
        for (int off = 1; off < 64; off <<= 1) {
            int t = __shfl_up(v, off);
            if (lane >= off) v += t;
        }
        if (lane == 63) wsum[wv] = v;
        __syncthreads();
        if (wv == 0) {
            int s = (lane < 16) ? wsum[lane] : 0;
            #pragma unroll
            for (int off = 1; off < 16; off <<= 1) {
                int t = __shfl_up(s, off);
                if (lane >= off) s += t;
            }
            if (lane < 16) wsum[lane] = s;
        }
        __syncthreads();
        const int carry = carry_s;
        const int woff  = (wv == 0) ? 0 : wsum[wv - 1];
        const int excl  = carry + woff + v - orig;
        if (i < N_NODES) { rowptr[i] = excl; cursor[i] = excl; }
        __syncthreads();
        if (tid == 0) carry_s += wsum[15];
        __syncthreads();
    }
    if (threadIdx.x == 0) rowptr[N_NODES] = carry_s;
}

__global__ __launch_bounds__(256) void scatter_kernel(
    const int* __restrict__ eidx, int* __restrict__ cursor, int* __restrict__ csr_src)
{
    const int e = blockIdx.x * blockDim.x + threadIdx.x;
    if (e >= E_TOT) return;
    int s, d;
    if (e < E_RAW) { s = eidx[e]; d = eidx[E_RAW + e]; }
    else           { s = d = e - E_RAW; }
    const int pos = atomicAdd(&cursor[d], 1);
    csr_src[pos] = s;
}

// ---------------------------------------------------------------------------
// Fused layer-1 GAT: one wave per dst node. score+softmax+aggregate+bias+skip+relu
// ---------------------------------------------------------------------------
__global__ __launch_bounds__(256) void fused1_kernel(
    const float* __restrict__ xl, const float* __restrict__ xr,
    const float* __restrict__ lin,
    const int* __restrict__ rowptr, const int* __restrict__ csr_src,
    const float* __restrict__ att, const float* __restrict__ b1,
    const float* __restrict__ blin1,
    float* __restrict__ h)
{
    const int gid  = blockIdx.x * blockDim.x + threadIdx.x;
    const int d    = gid >> 6;
    const int lane = gid & 63;
    if (d >= N_NODES) return;

    const int r0 = rowptr[d], r1 = rowptr[d + 1];
    const float2 xrd = ((const float2*)(xr + (size_t)d * 128))[lane];
    const float2 at  = ((const float2*)att)[lane];

    float num0 = 0.f, num1 = 0.f, den = 0.f;
    for (int j = r0; j < r1; ++j) {
        const int s = csr_src[j];
        const float2 a = ((const float2*)(xl + (size_t)s * 128))[lane];
        float m0 = a.x + xrd.x, m1 = a.y + xrd.y;
        m0 = m0 > 0.f ? m0 : NEG_SLOPE * m0;
        m1 = m1 > 0.f ? m1 : NEG_SLOPE * m1;
        float v = m0 * at.x + m1 * at.y;
        #pragma unroll
        for (int off = 32; off > 0; off >>= 1) v += __shfl_xor(v, off);
        const float ex = __expf(v);
        den += ex;
        num0 = fmaf(ex, a.x, num0);
        num1 = fmaf(ex, a.y, num1);
    }
    const float inv = 1.f / den;
    const float2 lv = ((const float2*)(lin   + (size_t)d * 128))[lane];
    const float2 bb = ((const float2*)b1)[lane];
    const float2 bl = ((const float2*)blin1)[lane];
    float h0 = fmaf(num0, inv, bb.x) + lv.x + bl.x;
    float h1 = fmaf(num1, inv, bb.y) + lv.y + bl.y;
    h0 = h0 > 0.f ? h0 : 0.f;
    h1 = h1 > 0.f ? h1 : 0.f;
    ((float2*)(h + (size_t)d * 128))[lane] = make_float2(h0, h1);
}

// ---------------------------------------------------------------------------
// Layer-2 small GEMM: one wave per row -> XL2, XR2, LIN2 (each [N,2])
// ---------------------------------------------------------------------------
__global__ __launch_bounds__(256) void gemm2_kernel(
    const float* __restrict__ h,
    const float* __restrict__ Wl2, const float* __restrict__ Wr2,
    const float* __restrict__ Wlin2,
    float* __restrict__ XL2, float* __restrict__ XR2, float* __restrict__ LIN2)
{
    const int gid  = blockIdx.x * blockDim.x + threadIdx.x;
    const int row  = gid >> 6;
    const int lane = gid & 63;
    if (row >= N_NODES) return;

    const float2 hv = ((const float2*)(h + (size_t)row * 128))[lane];
    const int k0 = 2 * lane, k1 = 2 * lane + 1;

    float v[6];
    v[0] = hv.x * Wl2[k0*2+0]   + hv.y * Wl2[k1*2+0];
    v[1] = hv.x * Wl2[k0*2+1]   + hv.y * Wl2[k1*2+1];
    v[2] = hv.x * Wr2[k0*2+0]   + hv.y * Wr2[k1*2+0];
    v[3] = hv.x * Wr2[k0*2+1]   + hv.y * Wr2[k1*2+1];
    v[4] = hv.x * Wlin2[k0*2+0] + hv.y * Wlin2[k1*2+0];
    v[5] = hv.x * Wlin2[k0*2+1] + hv.y * Wlin2[k1*2+1];

    #pragma unroll
    for (int off = 32; off > 0; off >>= 1) {
        #pragma unroll
        for (int j = 0; j < 6; ++j) v[j] += __shfl_xor(v[j], off);
    }

    if (lane == 0) {
        XL2[row*2+0]  = v[0]; XL2[row*2+1]  = v[1];
        XR2[row*2+0]  = v[2]; XR2[row*2+1]  = v[3];
        LIN2[row*2+0] = v[4]; LIN2[row*2+1] = v[5];
    }
}

// ---------------------------------------------------------------------------
// Fused layer-2 GAT + bias + skip + log_softmax: one thread per node.
// ---------------------------------------------------------------------------
__global__ __launch_bounds__(256) void fused2_kernel(
    const float* __restrict__ XL2, const float* __restrict__ XR2,
    const float* __restrict__ LIN2,
    const int* __restrict__ rowptr, const int* __restrict__ csr_src,
    const float* __restrict__ att2, const float* __restrict__ b2,
    const float* __restrict__ blin2,
    float* __restrict__ out)
{
    const int d = blockIdx.x * blockDim.x + threadIdx.x;
    if (d >= N_NODES) return;

    const int r0 = rowptr[d], r1 = rowptr[d + 1];
    const float xr0 = XR2[d*2+0], xr1 = XR2[d*2+1];
    const float a0 = att2[0], a1 = att2[1];

    float num0 = 0.f, num1 = 0.f, den = 0.f;
    for (int j = r0; j < r1; ++j) {
        const int s = csr_src[j];
        const float l0 = XL2[s*2+0], l1 = XL2[s*2+1];
        float m0 = l0 + xr0, m1 = l1 + xr1;
        m0 = m0 > 0.f ? m0 : NEG_SLOPE * m0;
        m1 = m1 > 0.f ? m1 : NEG_SLOPE * m1;
        const float ex = __expf(m0 * a0 + m1 * a1);
        den += ex;
        num0 = fmaf(ex, l0, num0);
        num1 = fmaf(ex, l1, num1);
    }
    const float inv = 1.f / den;
    const float o0 = num0 * inv + b2[0] + LIN2[d*2+0] + blin2[0];
    const float o1 = num1 * inv + b2[1] + LIN2[d*2+1] + blin2[1];
    const float mx  = fmaxf(o0, o1);
    const float lse = mx + logf(__expf(o0 - mx) + __expf(o1 - mx));
    out[d*2+0] = o0 - lse;
    out[d*2+1] = o1 - lse;
}

// ---------------------------------------------------------------------------
// copy edge_index (int32) -> d_out tail as float32
// ---------------------------------------------------------------------------
__global__ __launch_bounds__(256) void copy_eidx_kernel(
    const int* __restrict__ eidx, float* __restrict__ out)
{
    const int i = blockIdx.x * blockDim.x + threadIdx.x;
    if (i >= 2 * E_RAW) return;
    out[i] = (float)eidx[i];
}

// ---------------------------------------------------------------------------
extern "C" void kernel_launch(void* const* d_in, const int* in_sizes, int n_in,
                              void* d_out, int out_size, void* d_ws, size_t ws_size,
                              hipStream_t stream)
{
    const float* x      = (const float*)d_in[0];
    const int*   eidx   = (const int*)  d_in[1];
    const float* Wl1    = (const float*)d_in[2];
    const float* Wr1    = (const float*)d_in[3];
    const float* att1   = (const float*)d_in[4];
    const float* b1     = (const float*)d_in[5];
    const float* Wlin1  = (const float*)d_in[6];
    const float* blin1  = (const float*)d_in[7];
    const float* Wl2    = (const float*)d_in[8];
    const float* Wr2    = (const float*)d_in[9];
    const float* att2   = (const float*)d_in[10];
    const float* b2     = (const float*)d_in[11];
    const float* Wlin2  = (const float*)d_in[12];
    const float* blin2  = (const float*)d_in[13];

    float* out = (float*)d_out;

    // workspace layout (4-byte elements)
    float* ws     = (float*)d_ws;
    float* XL     = ws;                        // [N,128]
    float* XR     = ws + 6400000;              // [N,128]  (fused1 writes H in-place)
    float* LIN    = ws + 12800000;             // [N,128]  (reused for layer-2 vecs)
    int*   counts = (int*)(ws + 19200000);     // [N]  (also scatter cursor)
    int*   rowptr = counts + 50000;            // [N+1]
    int*   csr    = rowptr + 50001;            // [E_TOT]
    float* H      = XR;
    float* XL2    = LIN;                       // [N,2] — LIN data dead after fused1
    float* XR2    = LIN + 100000;
    float* LIN2   = LIN + 200000;

    // --- Layer-1 GEMM (LDS-tiled, single-buffer) ---
    {
        dim3 grid((N_NODES + TRR - 1) / TRR, 6);
        gemm1_kernel<<<grid, 256, 0, stream>>>(x, Wl1, Wr1, Wlin1, XL, XR, LIN);
    }

    // --- CSR build ---
    hipMemsetAsync(counts, 0, N_NODES * sizeof(int), stream);
    hist_kernel<<<(E_TOT + 255) / 256, 256, 0, stream>>>(eidx, counts);
    scan_kernel<<<1, 1024, 0, stream>>>(counts, rowptr, counts);
    scatter_kernel<<<(E_TOT + 255) / 256, 256, 0, stream>>>(eidx, counts, csr);

    // --- Fused layer-1 GAT (wave per node) ---
    {
        const int blocks = (N_NODES * 64 + 255) / 256;
        fused1_kernel<<<blocks, 256, 0, stream>>>(XL, XR, LIN, rowptr, csr,
                                                  att1, b1, blin1, H);
    }

    // --- Layer 2 ---
    {
        const int blocks = (N_NODES * 64 + 255) / 256;
        gemm2_kernel<<<blocks, 256, 0, stream>>>(H, Wl2, Wr2, Wlin2, XL2, XR2, LIN2);
    }
    {
        const int blocks = (N_NODES + 255) / 256;
        fused2_kernel<<<blocks, 256, 0, stream>>>(XL2, XR2, LIN2, rowptr, csr,
                                                  att2, b2, blin2, out);
    }
    {
        const int blocks = (2 * E_RAW + 255) / 256;
        copy_eidx_kernel<<<blocks, 256, 0, stream>>>(eidx, out + (size_t)N_NODES * 2);
    }
}

// Round 8
// 407.703 us; speedup vs baseline: 6.9627x; 1.1195x over previous
//
#include <hip/hip_runtime.h>
#include <math.h>

#define N_NODES 50000
#define F_IN 128
#define E_RAW 800000
#define E_TOT (E_RAW + N_NODES)   // self-loops appended
#define NEG_SLOPE 0.2f

// ---------------------------------------------------------------------------
// Kernel 1: LDS-tiled fused GEMM  X[N,128] @ [Wl1|Wr1|Wlin1] -> XL, XR, LIN
// (round-6 verified: single LDS buffer, runtime chunk loop, no spill)
// ---------------------------------------------------------------------------
#define TRR 128      // tile rows
#define TCC 64       // tile cols
#define KBB 32       // k chunk
#define XTS 132      // XT row stride in floats (128 + 4 pad)

__global__ __launch_bounds__(256, 4) void gemm1_kernel(
    const float* __restrict__ x,
    const float* __restrict__ Wl, const float* __restrict__ Wr,
    const float* __restrict__ Wlin,
    float* __restrict__ XL, float* __restrict__ XR, float* __restrict__ LIN)
{
    __shared__ float XT[KBB][XTS];   // [k][row] transposed X tile
    __shared__ float WS[KBB][TCC];   // [k][col]

    const int t  = threadIdx.x;
    const int tx = t & 15;
    const int ty = t >> 4;

    const int r0   = blockIdx.x * TRR;
    const int half = blockIdx.y & 1;
    const int mat  = blockIdx.y >> 1;     // 0=Wl 1=Wr 2=Wlin
    const int cs0  = half * 64;

    const float* Wsel = (mat == 0) ? Wl : (mat == 1) ? Wr : Wlin;
    float*       Osel = (mat == 0) ? XL : (mat == 1) ? XR : LIN;

    const int sx_k4  = t & 7;
    const int sx_row = t >> 3;

    float acc[8][4];
    #pragma unroll
    for (int r = 0; r < 8; ++r)
        #pragma unroll
        for (int c = 0; c < 4; ++c) acc[r][c] = 0.f;

    for (int kc = 0; kc < 128; kc += KBB) {
        #pragma unroll
        for (int i = 0; i < 4; ++i) {
            const int row = sx_row + i * 32;
            const int gr  = r0 + row;
            float4 v = (gr < N_NODES)
                ? *(const float4*)(x + (size_t)gr * 128 + kc + sx_k4 * 4)
                : make_float4(0.f, 0.f, 0.f, 0.f);
            XT[sx_k4 * 4 + 0][row] = v.x;
            XT[sx_k4 * 4 + 1][row] = v.y;
            XT[sx_k4 * 4 + 2][row] = v.z;
            XT[sx_k4 * 4 + 3][row] = v.w;
        }
        #pragma unroll
        for (int i = 0; i < 2; ++i) {
            const int wk = (t >> 4) + i * 16;
            float4 wv = *(const float4*)(Wsel + (size_t)(kc + wk) * 128 + cs0 + tx * 4);
            *(float4*)&WS[wk][tx * 4] = wv;
        }
        __syncthreads();

        #pragma unroll 8
        for (int k = 0; k < KBB; ++k) {
            const float4 xlo = *(const float4*)&XT[k][ty * 8];
            const float4 xhi = *(const float4*)&XT[k][ty * 8 + 4];
            const float4 wv  = *(const float4*)&WS[k][tx * 4];
            const float xs[8] = {xlo.x, xlo.y, xlo.z, xlo.w,
                                 xhi.x, xhi.y, xhi.z, xhi.w};
            #pragma unroll
            for (int r = 0; r < 8; ++r) {
                acc[r][0] = fmaf(xs[r], wv.x, acc[r][0]);
                acc[r][1] = fmaf(xs[r], wv.y, acc[r][1]);
                acc[r][2] = fmaf(xs[r], wv.z, acc[r][2]);
                acc[r][3] = fmaf(xs[r], wv.w, acc[r][3]);
            }
        }
        __syncthreads();
    }

    #pragma unroll
    for (int r = 0; r < 8; ++r) {
        const int grow = r0 + ty * 8 + r;
        if (grow < N_NODES) {
            float4 o = make_float4(acc[r][0], acc[r][1], acc[r][2], acc[r][3]);
            *(float4*)(Osel + (size_t)grow * 128 + cs0 + tx * 4) = o;
        }
    }
}

// ---------------------------------------------------------------------------
// CSR build: histogram of dst, exclusive scan, scatter src ids
// ---------------------------------------------------------------------------
__global__ __launch_bounds__(256) void hist_kernel(
    const int* __restrict__ eidx, int* __restrict__ counts)
{
    const int e = blockIdx.x * blockDim.x + threadIdx.x;
    if (e >= E_TOT) return;
    const int d = (e < E_RAW) ? eidx[E_RAW + e] : e - E_RAW;
    atomicAdd(&counts[d], 1);
}

__global__ __launch_bounds__(1024) void scan_kernel(
    const int* __restrict__ counts, int* __restrict__ rowptr, int* __restrict__ cursor)
{
    __shared__ int wsum[16];
    __shared__ int carry_s;
    const int tid = threadIdx.x, lane = tid & 63, wv = tid >> 6;
    if (tid == 0) carry_s = 0;
    __syncthreads();

    for (int base = 0; base < N_NODES; base += 1024) {
        const int i = base + tid;
        const int orig = (i < N_NODES) ? counts[i] : 0;
        int v = orig;
        #pragma unroll
        for (int off = 1; off < 64; off <<= 1) {
            int t = __shfl_up(v, off);
            if (lane >= off) v += t;
        }
        if (lane == 63) wsum[wv] = v;
        __syncthreads();
        if (wv == 0) {
            int s = (lane < 16) ? wsum[lane] : 0;
            #pragma unroll
            for (int off = 1; off < 16; off <<= 1) {
                int t = __shfl_up(s, off);
                if (lane >= off) s += t;
            }
            if (lane < 16) wsum[lane] = s;
        }
        __syncthreads();
        const int carry = carry_s;
        const int woff  = (wv == 0) ? 0 : wsum[wv - 1];
        const int excl  = carry + woff + v - orig;
        if (i < N_NODES) { rowptr[i] = excl; cursor[i] = excl; }
        __syncthreads();
        if (tid == 0) carry_s += wsum[15];
        __syncthreads();
    }
    if (threadIdx.x == 0) rowptr[N_NODES] = carry_s;
}

__global__ __launch_bounds__(256) void scatter_kernel(
    const int* __restrict__ eidx, int* __restrict__ cursor, int* __restrict__ csr_src)
{
    const int e = blockIdx.x * blockDim.x + threadIdx.x;
    if (e >= E_TOT) return;
    int s, d;
    if (e < E_RAW) { s = eidx[e]; d = eidx[E_RAW + e]; }
    else           { s = d = e - E_RAW; }
    const int pos = atomicAdd(&cursor[d], 1);
    csr_src[pos] = s;
}

// ---------------------------------------------------------------------------
// Fused layer-1 GAT v2: one wave per dst node, 4 edges in flight.
// grp = lane>>4 selects edge slot; sub = lane&15 covers dims sub*8..sub*8+7.
// Score reduce: 4-step butterfly within 16 lanes. num/den combined across
// groups once per node (2 shfl steps). Invalid edge slots -> ex = 0 (select).
// ---------------------------------------------------------------------------
__global__ __launch_bounds__(256) void fused1_kernel(
    const float* __restrict__ xl, const float* __restrict__ xr,
    const float* __restrict__ lin,
    const int* __restrict__ rowptr, const int* __restrict__ csr_src,
    const float* __restrict__ att, const float* __restrict__ b1,
    const float* __restrict__ blin1,
    float* __restrict__ h)
{
    const int gid  = blockIdx.x * blockDim.x + threadIdx.x;
    const int d    = gid >> 6;
    const int lane = gid & 63;
    if (d >= N_NODES) return;
    const int grp = lane >> 4;      // edge slot 0..3
    const int sub = lane & 15;      // dim group

    const int r0 = rowptr[d], r1 = rowptr[d + 1];

    const float4 xr0 = *(const float4*)(xr + (size_t)d * 128 + sub * 8);
    const float4 xr1 = *(const float4*)(xr + (size_t)d * 128 + sub * 8 + 4);
    const float4 at0 = *(const float4*)(att + sub * 8);
    const float4 at1 = *(const float4*)(att + sub * 8 + 4);

    float num[8] = {0.f,0.f,0.f,0.f,0.f,0.f,0.f,0.f};
    float den = 0.f;

    for (int j = r0; j < r1; j += 4) {
        const int e  = j + grp;
        const int ee = (e < E_TOT) ? e : (E_TOT - 1);
        const int s  = csr_src[ee];
        const float4 a0 = *(const float4*)(xl + (size_t)s * 128 + sub * 8);
        const float4 a1 = *(const float4*)(xl + (size_t)s * 128 + sub * 8 + 4);

        float m, v = 0.f;
        m = a0.x + xr0.x; m = m > 0.f ? m : NEG_SLOPE * m; v = fmaf(m, at0.x, v);
        m = a0.y + xr0.y; m = m > 0.f ? m : NEG_SLOPE * m; v = fmaf(m, at0.y, v);
        m = a0.z + xr0.z; m = m > 0.f ? m : NEG_SLOPE * m; v = fmaf(m, at0.z, v);
        m = a0.w + xr0.w; m = m > 0.f ? m : NEG_SLOPE * m; v = fmaf(m, at0.w, v);
        m = a1.x + xr1.x; m = m > 0.f ? m : NEG_SLOPE * m; v = fmaf(m, at1.x, v);
        m = a1.y + xr1.y; m = m > 0.f ? m : NEG_SLOPE * m; v = fmaf(m, at1.y, v);
        m = a1.z + xr1.z; m = m > 0.f ? m : NEG_SLOPE * m; v = fmaf(m, at1.z, v);
        m = a1.w + xr1.w; m = m > 0.f ? m : NEG_SLOPE * m; v = fmaf(m, at1.w, v);

        v += __shfl_xor(v, 1);
        v += __shfl_xor(v, 2);
        v += __shfl_xor(v, 4);
        v += __shfl_xor(v, 8);

        const float ex = (e < r1) ? __expf(v) : 0.f;
        den += ex;
        num[0] = fmaf(ex, a0.x, num[0]);
        num[1] = fmaf(ex, a0.y, num[1]);
        num[2] = fmaf(ex, a0.z, num[2]);
        num[3] = fmaf(ex, a0.w, num[3]);
        num[4] = fmaf(ex, a1.x, num[4]);
        num[5] = fmaf(ex, a1.y, num[5]);
        num[6] = fmaf(ex, a1.z, num[6]);
        num[7] = fmaf(ex, a1.w, num[7]);
    }

    // combine the 4 edge groups (lanes with same sub hold the same dims)
    den += __shfl_xor(den, 16);
    den += __shfl_xor(den, 32);
    #pragma unroll
    for (int i = 0; i < 8; ++i) {
        num[i] += __shfl_xor(num[i], 16);
        num[i] += __shfl_xor(num[i], 32);
    }

    if (grp == 0) {
        const float inv = 1.f / den;
        const float4 l0  = *(const float4*)(lin   + (size_t)d * 128 + sub * 8);
        const float4 l1  = *(const float4*)(lin   + (size_t)d * 128 + sub * 8 + 4);
        const float4 bb0 = *(const float4*)(b1    + sub * 8);
        const float4 bb1 = *(const float4*)(b1    + sub * 8 + 4);
        const float4 bl0 = *(const float4*)(blin1 + sub * 8);
        const float4 bl1 = *(const float4*)(blin1 + sub * 8 + 4);
        float4 o0, o1;
        o0.x = fmaf(num[0], inv, bb0.x) + l0.x + bl0.x;
        o0.y = fmaf(num[1], inv, bb0.y) + l0.y + bl0.y;
        o0.z = fmaf(num[2], inv, bb0.z) + l0.z + bl0.z;
        o0.w = fmaf(num[3], inv, bb0.w) + l0.w + bl0.w;
        o1.x = fmaf(num[4], inv, bb1.x) + l1.x + bl1.x;
        o1.y = fmaf(num[5], inv, bb1.y) + l1.y + bl1.y;
        o1.z = fmaf(num[6], inv, bb1.z) + l1.z + bl1.z;
        o1.w = fmaf(num[7], inv, bb1.w) + l1.w + bl1.w;
        o0.x = o0.x > 0.f ? o0.x : 0.f;  o0.y = o0.y > 0.f ? o0.y : 0.f;
        o0.z = o0.z > 0.f ? o0.z : 0.f;  o0.w = o0.w > 0.f ? o0.w : 0.f;
        o1.x = o1.x > 0.f ? o1.x : 0.f;  o1.y = o1.y > 0.f ? o1.y : 0.f;
        o1.z = o1.z > 0.f ? o1.z : 0.f;  o1.w = o1.w > 0.f ? o1.w : 0.f;
        *(float4*)(h + (size_t)d * 128 + sub * 8)     = o0;
        *(float4*)(h + (size_t)d * 128 + sub * 8 + 4) = o1;
    }
}

// ---------------------------------------------------------------------------
// Layer-2 small GEMM: one wave per row -> XL2, XR2, LIN2 (each [N,2])
// ---------------------------------------------------------------------------
__global__ __launch_bounds__(256) void gemm2_kernel(
    const float* __restrict__ h,
    const float* __restrict__ Wl2, const float* __restrict__ Wr2,
    const float* __restrict__ Wlin2,
    float* __restrict__ XL2, float* __restrict__ XR2, float* __restrict__ LIN2)
{
    const int gid  = blockIdx.x * blockDim.x + threadIdx.x;
    const int row  = gid >> 6;
    const int lane = gid & 63;
    if (row >= N_NODES) return;

    const float2 hv = ((const float2*)(h + (size_t)row * 128))[lane];
    const int k0 = 2 * lane, k1 = 2 * lane + 1;

    float v[6];
    v[0] = hv.x * Wl2[k0*2+0]   + hv.y * Wl2[k1*2+0];
    v[1] = hv.x * Wl2[k0*2+1]   + hv.y * Wl2[k1*2+1];
    v[2] = hv.x * Wr2[k0*2+0]   + hv.y * Wr2[k1*2+0];
    v[3] = hv.x * Wr2[k0*2+1]   + hv.y * Wr2[k1*2+1];
    v[4] = hv.x * Wlin2[k0*2+0] + hv.y * Wlin2[k1*2+0];
    v[5] = hv.x * Wlin2[k0*2+1] + hv.y * Wlin2[k1*2+1];

    #pragma unroll
    for (int off = 32; off > 0; off >>= 1) {
        #pragma unroll
        for (int j = 0; j < 6; ++j) v[j] += __shfl_xor(v[j], off);
    }

    if (lane == 0) {
        XL2[row*2+0]  = v[0]; XL2[row*2+1]  = v[1];
        XR2[row*2+0]  = v[2]; XR2[row*2+1]  = v[3];
        LIN2[row*2+0] = v[4]; LIN2[row*2+1] = v[5];
    }
}

// ---------------------------------------------------------------------------
// Fused layer-2 GAT + bias + skip + log_softmax: one thread per node.
// ---------------------------------------------------------------------------
__global__ __launch_bounds__(256) void fused2_kernel(
    const float* __restrict__ XL2, const float* __restrict__ XR2,
    const float* __restrict__ LIN2,
    const int* __restrict__ rowptr, const int* __restrict__ csr_src,
    const float* __restrict__ att2, const float* __restrict__ b2,
    const float* __restrict__ blin2,
    float* __restrict__ out)
{
    const int d = blockIdx.x * blockDim.x + threadIdx.x;
    if (d >= N_NODES) return;

    const int r0 = rowptr[d], r1 = rowptr[d + 1];
    const float xr0 = XR2[d*2+0], xr1 = XR2[d*2+1];
    const float a0 = att2[0], a1 = att2[1];

    float num0 = 0.f, num1 = 0.f, den = 0.f;
    for (int j = r0; j < r1; ++j) {
        const int s = csr_src[j];
        const float l0 = XL2[s*2+0], l1 = XL2[s*2+1];
        float m0 = l0 + xr0, m1 = l1 + xr1;
        m0 = m0 > 0.f ? m0 : NEG_SLOPE * m0;
        m1 = m1 > 0.f ? m1 : NEG_SLOPE * m1;
        const float ex = __expf(m0 * a0 + m1 * a1);
        den += ex;
        num0 = fmaf(ex, l0, num0);
        num1 = fmaf(ex, l1, num1);
    }
    const float inv = 1.f / den;
    const float o0 = num0 * inv + b2[0] + LIN2[d*2+0] + blin2[0];
    const float o1 = num1 * inv + b2[1] + LIN2[d*2+1] + blin2[1];
    const float mx  = fmaxf(o0, o1);
    const float lse = mx + logf(__expf(o0 - mx) + __expf(o1 - mx));
    out[d*2+0] = o0 - lse;
    out[d*2+1] = o1 - lse;
}

// ---------------------------------------------------------------------------
// copy edge_index (int32) -> d_out tail as float32
// ---------------------------------------------------------------------------
__global__ __launch_bounds__(256) void copy_eidx_kernel(
    const int* __restrict__ eidx, float* __restrict__ out)
{
    const int i = blockIdx.x * blockDim.x + threadIdx.x;
    if (i >= 2 * E_RAW) return;
    out[i] = (float)eidx[i];
}

// ---------------------------------------------------------------------------
extern "C" void kernel_launch(void* const* d_in, const int* in_sizes, int n_in,
                              void* d_out, int out_size, void* d_ws, size_t ws_size,
                              hipStream_t stream)
{
    const float* x      = (const float*)d_in[0];
    const int*   eidx   = (const int*)  d_in[1];
    const float* Wl1    = (const float*)d_in[2];
    const float* Wr1    = (const float*)d_in[3];
    const float* att1   = (const float*)d_in[4];
    const float* b1     = (const float*)d_in[5];
    const float* Wlin1  = (const float*)d_in[6];
    const float* blin1  = (const float*)d_in[7];
    const float* Wl2    = (const float*)d_in[8];
    const float* Wr2    = (const float*)d_in[9];
    const float* att2   = (const float*)d_in[10];
    const float* b2     = (const float*)d_in[11];
    const float* Wlin2  = (const float*)d_in[12];
    const float* blin2  = (const float*)d_in[13];

    float* out = (float*)d_out;

    // workspace layout (4-byte elements)
    float* ws     = (float*)d_ws;
    float* XL     = ws;                        // [N,128]
    float* XR     = ws + 6400000;              // [N,128]  (fused1 writes H in-place)
    float* LIN    = ws + 12800000;             // [N,128]  (reused for layer-2 vecs)
    int*   counts = (int*)(ws + 19200000);     // [N]  (also scatter cursor)
    int*   rowptr = counts + 50000;            // [N+1]
    int*   csr    = rowptr + 50001;            // [E_TOT]
    float* H      = XR;
    float* XL2    = LIN;                       // [N,2] — LIN data dead after fused1
    float* XR2    = LIN + 100000;
    float* LIN2   = LIN + 200000;

    // --- Layer-1 GEMM (LDS-tiled, single-buffer) ---
    {
        dim3 grid((N_NODES + TRR - 1) / TRR, 6);
        gemm1_kernel<<<grid, 256, 0, stream>>>(x, Wl1, Wr1, Wlin1, XL, XR, LIN);
    }

    // --- CSR build ---
    hipMemsetAsync(counts, 0, N_NODES * sizeof(int), stream);
    hist_kernel<<<(E_TOT + 255) / 256, 256, 0, stream>>>(eidx, counts);
    scan_kernel<<<1, 1024, 0, stream>>>(counts, rowptr, counts);
    scatter_kernel<<<(E_TOT + 255) / 256, 256, 0, stream>>>(eidx, counts, csr);

    // --- Fused layer-1 GAT (wave per node, 4-edge groups) ---
    {
        const int blocks = (N_NODES * 64 + 255) / 256;
        fused1_kernel<<<blocks, 256, 0, stream>>>(XL, XR, LIN, rowptr, csr,
                                                  att1, b1, blin1, H);
    }

    // --- Layer 2 ---
    {
        const int blocks = (N_NODES * 64 + 255) / 256;
        gemm2_kernel<<<blocks, 256, 0, stream>>>(H, Wl2, Wr2, Wlin2, XL2, XR2, LIN2);
    }
    {
        const int blocks = (N_NODES + 255) / 256;
        fused2_kernel<<<blocks, 256, 0, stream>>>(XL2, XR2, LIN2, rowptr, csr,
                                                  att2, b2, blin2, out);
    }
    {
        const int blocks = (2 * E_RAW + 255) / 256;
        copy_eidx_kernel<<<blocks, 256, 0, stream>>>(eidx, out + (size_t)N_NODES * 2);
    }
}

// Round 10
// 392.545 us; speedup vs baseline: 7.2315x; 1.0386x over previous
//
#include <hip/hip_runtime.h>
#include <math.h>

#define N_NODES 50000
#define F_IN 128
#define E_RAW 800000
#define E_TOT (E_RAW + N_NODES)   // self-loops appended
#define NEG_SLOPE 0.2f

// ---------------------------------------------------------------------------
// Kernel 1: LDS-tiled fused GEMM  X[N,128] @ [Wl1|Wr1|Wlin1] -> XL, XR, LIN
// Round-9: non-transposed XS[row][k] with ODD pad (33) — staging writes <=2-way
// (free), compute reads are 16-lane broadcasts across 4 banks (conflict-free).
// Round-8 transposed layout had a 4-way write conflict (3.6M SQ_LDS_BANK_CONFLICT).
// ---------------------------------------------------------------------------
#define TRR 128      // tile rows
#define TCC 64       // tile cols
#define KBB 32       // k chunk
#define XP33 33      // odd pad: row stride 33 floats

__global__ __launch_bounds__(256, 4) void gemm1_kernel(
    const float* __restrict__ x,
    const float* __restrict__ Wl, const float* __restrict__ Wr,
    const float* __restrict__ Wlin,
    float* __restrict__ XL, float* __restrict__ XR, float* __restrict__ LIN)
{
    __shared__ float XS[TRR][XP33];  // [row][k]  16.9 KB
    __shared__ float WS[KBB][TCC];   // [k][col]  8 KB

    const int t  = threadIdx.x;
    const int tx = t & 15;
    const int ty = t >> 4;

    const int r0   = blockIdx.x * TRR;
    const int half = blockIdx.y & 1;
    const int mat  = blockIdx.y >> 1;     // 0=Wl 1=Wr 2=Wlin
    const int cs0  = half * 64;

    const float* Wsel = (mat == 0) ? Wl : (mat == 1) ? Wr : Wlin;
    float*       Osel = (mat == 0) ? XL : (mat == 1) ? XR : LIN;

    const int sx_k4  = t & 7;    // float4 index within the 32-k chunk
    const int sx_row = t >> 3;   // row 0..31 (+32*i)

    float acc[8][4];
    #pragma unroll
    for (int r = 0; r < 8; ++r)
        #pragma unroll
        for (int c = 0; c < 4; ++c) acc[r][c] = 0.f;

    for (int kc = 0; kc < 128; kc += KBB) {
        // stage X chunk: coalesced float4 reads, scalar LDS writes (<=2-way)
        #pragma unroll
        for (int i = 0; i < 4; ++i) {
            const int row = sx_row + i * 32;
            const int gr  = r0 + row;
            float4 v = (gr < N_NODES)
                ? *(const float4*)(x + (size_t)gr * 128 + kc + sx_k4 * 4)
                : make_float4(0.f, 0.f, 0.f, 0.f);
            XS[row][sx_k4 * 4 + 0] = v.x;
            XS[row][sx_k4 * 4 + 1] = v.y;
            XS[row][sx_k4 * 4 + 2] = v.z;
            XS[row][sx_k4 * 4 + 3] = v.w;
        }
        // stage W chunk (b128 writes, 2-way max)
        #pragma unroll
        for (int i = 0; i < 2; ++i) {
            const int wk = (t >> 4) + i * 16;
            float4 wv = *(const float4*)(Wsel + (size_t)(kc + wk) * 128 + cs0 + tx * 4);
            *(float4*)&WS[wk][tx * 4] = wv;
        }
        __syncthreads();

        // compute: per k, 8 broadcast b32 X reads + 1 b128 W read + 32 FMA
        #pragma unroll 8
        for (int k = 0; k < KBB; ++k) {
            const float4 wv = *(const float4*)&WS[k][tx * 4];
            float xv[8];
            #pragma unroll
            for (int r = 0; r < 8; ++r) xv[r] = XS[ty * 8 + r][k];
            #pragma unroll
            for (int r = 0; r < 8; ++r) {
                acc[r][0] = fmaf(xv[r], wv.x, acc[r][0]);
                acc[r][1] = fmaf(xv[r], wv.y, acc[r][1]);
                acc[r][2] = fmaf(xv[r], wv.z, acc[r][2]);
                acc[r][3] = fmaf(xv[r], wv.w, acc[r][3]);
            }
        }
        __syncthreads();
    }

    #pragma unroll
    for (int r = 0; r < 8; ++r) {
        const int grow = r0 + ty * 8 + r;
        if (grow < N_NODES) {
            float4 o = make_float4(acc[r][0], acc[r][1], acc[r][2], acc[r][3]);
            *(float4*)(Osel + (size_t)grow * 128 + cs0 + tx * 4) = o;
        }
    }
}

// ---------------------------------------------------------------------------
// CSR build: histogram of dst, exclusive scan, scatter src ids
// ---------------------------------------------------------------------------
__global__ __launch_bounds__(256) void hist_kernel(
    const int* __restrict__ eidx, int* __restrict__ counts)
{
    const int e = blockIdx.x * blockDim.x + threadIdx.x;
    if (e >= E_TOT) return;
    const int d = (e < E_RAW) ? eidx[E_RAW + e] : e - E_RAW;
    atomicAdd(&counts[d], 1);
}

__global__ __launch_bounds__(1024) void scan_kernel(
    const int* __restrict__ counts, int* __restrict__ rowptr, int* __restrict__ cursor)
{
    __shared__ int wsum[16];
    __shared__ int carry_s;
    const int tid = threadIdx.x, lane = tid & 63, wv = tid >> 6;
    if (tid == 0) carry_s = 0;
    __syncthreads();

    for (int base = 0; base < N_NODES; base += 1024) {
        const int i = base + tid;
        const int orig = (i < N_NODES) ? counts[i] : 0;
        int v = orig;
        #pragma unroll
        for (int off = 1; off < 64; off <<= 1) {
            int t = __shfl_up(v, off);
            if (lane >= off) v += t;
        }
        if (lane == 63) wsum[wv] = v;
        __syncthreads();
        if (wv == 0) {
            int s = (lane < 16) ? wsum[lane] : 0;
            #pragma unroll
            for (int off = 1; off < 16; off <<= 1) {
                int t = __shfl_up(s, off);
                if (lane >= off) s += t;
            }
            if (lane < 16) wsum[lane] = s;
        }
        __syncthreads();
        const int carry = carry_s;
        const int woff  = (wv == 0) ? 0 : wsum[wv - 1];
        const int excl  = carry + woff + v - orig;
        if (i < N_NODES) { rowptr[i] = excl; cursor[i] = excl; }
        __syncthreads();
        if (tid == 0) carry_s += wsum[15];
        __syncthreads();
    }
    if (threadIdx.x == 0) rowptr[N_NODES] = carry_s;
}

__global__ __launch_bounds__(256) void scatter_kernel(
    const int* __restrict__ eidx, int* __restrict__ cursor, int* __restrict__ csr_src)
{
    const int e = blockIdx.x * blockDim.x + threadIdx.x;
    if (e >= E_TOT) return;
    int s, d;
    if (e < E_RAW) { s = eidx[e]; d = eidx[E_RAW + e]; }
    else           { s = d = e - E_RAW; }
    const int pos = atomicAdd(&cursor[d], 1);
    csr_src[pos] = s;
}

// ---------------------------------------------------------------------------
// Fused layer-1 GAT v3: one wave per dst node, 4 edges in flight, PLUS fused
// layer-2 projections: after softmax-combine every lane holds num/den, so each
// lane computes its 8 h-dims (relu'd) and dots with Wl2/Wr2/Wlin2; 16-lane
// reduce; lane 0 writes XL2/XR2/LIN2. H is never materialized; gemm2 deleted.
// ---------------------------------------------------------------------------
__global__ __launch_bounds__(256) void fused1_kernel(
    const float* __restrict__ xl, const float* __restrict__ xr,
    const float* __restrict__ lin,
    const int* __restrict__ rowptr, const int* __restrict__ csr_src,
    const float* __restrict__ att, const float* __restrict__ b1,
    const float* __restrict__ blin1,
    const float* __restrict__ Wl2, const float* __restrict__ Wr2,
    const float* __restrict__ Wlin2,
    float* __restrict__ XL2, float* __restrict__ XR2, float* __restrict__ LIN2)
{
    const int gid  = blockIdx.x * blockDim.x + threadIdx.x;
    const int d    = gid >> 6;
    const int lane = gid & 63;
    if (d >= N_NODES) return;
    const int grp = lane >> 4;      // edge slot 0..3
    const int sub = lane & 15;      // dim group

    const int r0 = rowptr[d], r1 = rowptr[d + 1];

    const float4 xr0 = *(const float4*)(xr + (size_t)d * 128 + sub * 8);
    const float4 xr1 = *(const float4*)(xr + (size_t)d * 128 + sub * 8 + 4);
    const float4 at0 = *(const float4*)(att + sub * 8);
    const float4 at1 = *(const float4*)(att + sub * 8 + 4);

    float num[8] = {0.f,0.f,0.f,0.f,0.f,0.f,0.f,0.f};
    float den = 0.f;

    for (int j = r0; j < r1; j += 4) {
        const int e  = j + grp;
        const int ee = (e < E_TOT) ? e : (E_TOT - 1);
        const int s  = csr_src[ee];
        const float4 a0 = *(const float4*)(xl + (size_t)s * 128 + sub * 8);
        const float4 a1 = *(const float4*)(xl + (size_t)s * 128 + sub * 8 + 4);

        float m, v = 0.f;
        m = a0.x + xr0.x; m = m > 0.f ? m : NEG_SLOPE * m; v = fmaf(m, at0.x, v);
        m = a0.y + xr0.y; m = m > 0.f ? m : NEG_SLOPE * m; v = fmaf(m, at0.y, v);
        m = a0.z + xr0.z; m = m > 0.f ? m : NEG_SLOPE * m; v = fmaf(m, at0.z, v);
        m = a0.w + xr0.w; m = m > 0.f ? m : NEG_SLOPE * m; v = fmaf(m, at0.w, v);
        m = a1.x + xr1.x; m = m > 0.f ? m : NEG_SLOPE * m; v = fmaf(m, at1.x, v);
        m = a1.y + xr1.y; m = m > 0.f ? m : NEG_SLOPE * m; v = fmaf(m, at1.y, v);
        m = a1.z + xr1.z; m = m > 0.f ? m : NEG_SLOPE * m; v = fmaf(m, at1.z, v);
        m = a1.w + xr1.w; m = m > 0.f ? m : NEG_SLOPE * m; v = fmaf(m, at1.w, v);

        v += __shfl_xor(v, 1);
        v += __shfl_xor(v, 2);
        v += __shfl_xor(v, 4);
        v += __shfl_xor(v, 8);

        const float ex = (e < r1) ? __expf(v) : 0.f;
        den += ex;
        num[0] = fmaf(ex, a0.x, num[0]);
        num[1] = fmaf(ex, a0.y, num[1]);
        num[2] = fmaf(ex, a0.z, num[2]);
        num[3] = fmaf(ex, a0.w, num[3]);
        num[4] = fmaf(ex, a1.x, num[4]);
        num[5] = fmaf(ex, a1.y, num[5]);
        num[6] = fmaf(ex, a1.z, num[6]);
        num[7] = fmaf(ex, a1.w, num[7]);
    }

    // combine the 4 edge groups -> every lane holds full num/den
    den += __shfl_xor(den, 16);
    den += __shfl_xor(den, 32);
    #pragma unroll
    for (int i = 0; i < 8; ++i) {
        num[i] += __shfl_xor(num[i], 16);
        num[i] += __shfl_xor(num[i], 32);
    }

    // --- epilogue: h dims (relu) on ALL lanes (grps redundant), then W2 dots ---
    const float inv = 1.f / den;
    const float4 l0  = *(const float4*)(lin   + (size_t)d * 128 + sub * 8);
    const float4 l1  = *(const float4*)(lin   + (size_t)d * 128 + sub * 8 + 4);
    const float4 bb0 = *(const float4*)(b1    + sub * 8);
    const float4 bb1 = *(const float4*)(b1    + sub * 8 + 4);
    const float4 bl0 = *(const float4*)(blin1 + sub * 8);
    const float4 bl1 = *(const float4*)(blin1 + sub * 8 + 4);
    float h0 = fmaf(num[0], inv, bb0.x) + l0.x + bl0.x;
    float h1 = fmaf(num[1], inv, bb0.y) + l0.y + bl0.y;
    float h2 = fmaf(num[2], inv, bb0.z) + l0.z + bl0.z;
    float h3 = fmaf(num[3], inv, bb0.w) + l0.w + bl0.w;
    float h4 = fmaf(num[4], inv, bb1.x) + l1.x + bl1.x;
    float h5 = fmaf(num[5], inv, bb1.y) + l1.y + bl1.y;
    float h6 = fmaf(num[6], inv, bb1.z) + l1.z + bl1.z;
    float h7 = fmaf(num[7], inv, bb1.w) + l1.w + bl1.w;
    h0 = h0 > 0.f ? h0 : 0.f;  h1 = h1 > 0.f ? h1 : 0.f;
    h2 = h2 > 0.f ? h2 : 0.f;  h3 = h3 > 0.f ? h3 : 0.f;
    h4 = h4 > 0.f ? h4 : 0.f;  h5 = h5 > 0.f ? h5 : 0.f;
    h6 = h6 > 0.f ? h6 : 0.f;  h7 = h7 > 0.f ? h7 : 0.f;

    // W2 [128][2] row-major: float4 q covers rows 2i,2i+1: (q.x,q.y)=row0 c0,c1...
    float pl0, pl1, pr0, pr1, pn0, pn1;
    {
        const float4 a = ((const float4*)Wl2)[sub*4+0];
        const float4 b = ((const float4*)Wl2)[sub*4+1];
        const float4 c = ((const float4*)Wl2)[sub*4+2];
        const float4 e4= ((const float4*)Wl2)[sub*4+3];
        pl0 = h0*a.x + h1*a.z + h2*b.x + h3*b.z + h4*c.x + h5*c.z + h6*e4.x + h7*e4.z;
        pl1 = h0*a.y + h1*a.w + h2*b.y + h3*b.w + h4*c.y + h5*c.w + h6*e4.y + h7*e4.w;
    }
    {
        const float4 a = ((const float4*)Wr2)[sub*4+0];
        const float4 b = ((const float4*)Wr2)[sub*4+1];
        const float4 c = ((const float4*)Wr2)[sub*4+2];
        const float4 e4= ((const float4*)Wr2)[sub*4+3];
        pr0 = h0*a.x + h1*a.z + h2*b.x + h3*b.z + h4*c.x + h5*c.z + h6*e4.x + h7*e4.z;
        pr1 = h0*a.y + h1*a.w + h2*b.y + h3*b.w + h4*c.y + h5*c.w + h6*e4.y + h7*e4.w;
    }
    {
        const float4 a = ((const float4*)Wlin2)[sub*4+0];
        const float4 b = ((const float4*)Wlin2)[sub*4+1];
        const float4 c = ((const float4*)Wlin2)[sub*4+2];
        const float4 e4= ((const float4*)Wlin2)[sub*4+3];
        pn0 = h0*a.x + h1*a.z + h2*b.x + h3*b.z + h4*c.x + h5*c.z + h6*e4.x + h7*e4.z;
        pn1 = h0*a.y + h1*a.w + h2*b.y + h3*b.w + h4*c.y + h5*c.w + h6*e4.y + h7*e4.w;
    }
    #pragma unroll
    for (int off = 1; off < 16; off <<= 1) {
        pl0 += __shfl_xor(pl0, off); pl1 += __shfl_xor(pl1, off);
        pr0 += __shfl_xor(pr0, off); pr1 += __shfl_xor(pr1, off);
        pn0 += __shfl_xor(pn0, off); pn1 += __shfl_xor(pn1, off);
    }
    if (lane == 0) {
        XL2[d*2+0]  = pl0; XL2[d*2+1]  = pl1;
        XR2[d*2+0]  = pr0; XR2[d*2+1]  = pr1;
        LIN2[d*2+0] = pn0; LIN2[d*2+1] = pn1;
    }
}

// ---------------------------------------------------------------------------
// Fused layer-2 GAT + bias + skip + log_softmax: 16 lanes per node (edges
// strided across lanes -> 16 gather chains in flight vs 1).
// ---------------------------------------------------------------------------
__global__ __launch_bounds__(256) void fused2_kernel(
    const float* __restrict__ XL2, const float* __restrict__ XR2,
    const float* __restrict__ LIN2,
    const int* __restrict__ rowptr, const int* __restrict__ csr_src,
    const float* __restrict__ att2, const float* __restrict__ b2,
    const float* __restrict__ blin2,
    float* __restrict__ out)
{
    const int gid = blockIdx.x * blockDim.x + threadIdx.x;
    const int d   = gid >> 4;
    const int l16 = gid & 15;
    if (d >= N_NODES) return;

    const int r0 = rowptr[d], r1 = rowptr[d + 1];
    const float2 xrv = *(const float2*)(XR2 + (size_t)d * 2);
    const float a0 = att2[0], a1 = att2[1];

    float num0 = 0.f, num1 = 0.f, den = 0.f;
    for (int j = r0 + l16; j < r1; j += 16) {
        const int s = csr_src[j];
        const float2 l = *(const float2*)(XL2 + (size_t)s * 2);
        float m0 = l.x + xrv.x, m1 = l.y + xrv.y;
        m0 = m0 > 0.f ? m0 : NEG_SLOPE * m0;
        m1 = m1 > 0.f ? m1 : NEG_SLOPE * m1;
        const float ex = __expf(fmaf(m0, a0, m1 * a1));
        den += ex;
        num0 = fmaf(ex, l.x, num0);
        num1 = fmaf(ex, l.y, num1);
    }
    #pragma unroll
    for (int off = 1; off < 16; off <<= 1) {
        den  += __shfl_xor(den,  off);
        num0 += __shfl_xor(num0, off);
        num1 += __shfl_xor(num1, off);
    }
    if (l16 == 0) {
        const float inv = 1.f / den;
        const float o0 = num0 * inv + b2[0] + LIN2[d*2+0] + blin2[0];
        const float o1 = num1 * inv + b2[1] + LIN2[d*2+1] + blin2[1];
        const float mx  = fmaxf(o0, o1);
        const float lse = mx + logf(__expf(o0 - mx) + __expf(o1 - mx));
        out[d*2+0] = o0 - lse;
        out[d*2+1] = o1 - lse;
    }
}

// ---------------------------------------------------------------------------
// copy edge_index (int32) -> d_out tail as float32 (runs LAST: overwrites the
// XL2/XR2/LIN2 scratch staged in the out tail)
// ---------------------------------------------------------------------------
__global__ __launch_bounds__(256) void copy_eidx_kernel(
    const int* __restrict__ eidx, float* __restrict__ out)
{
    const int i = blockIdx.x * blockDim.x + threadIdx.x;
    if (i >= 2 * E_RAW) return;
    out[i] = (float)eidx[i];
}

// ---------------------------------------------------------------------------
extern "C" void kernel_launch(void* const* d_in, const int* in_sizes, int n_in,
                              void* d_out, int out_size, void* d_ws, size_t ws_size,
                              hipStream_t stream)
{
    const float* x      = (const float*)d_in[0];
    const int*   eidx   = (const int*)  d_in[1];
    const float* Wl1    = (const float*)d_in[2];
    const float* Wr1    = (const float*)d_in[3];
    const float* att1   = (const float*)d_in[4];
    const float* b1     = (const float*)d_in[5];
    const float* Wlin1  = (const float*)d_in[6];
    const float* blin1  = (const float*)d_in[7];
    const float* Wl2    = (const float*)d_in[8];
    const float* Wr2    = (const float*)d_in[9];
    const float* att2   = (const float*)d_in[10];
    const float* b2     = (const float*)d_in[11];
    const float* Wlin2  = (const float*)d_in[12];
    const float* blin2  = (const float*)d_in[13];

    float* out = (float*)d_out;

    // workspace layout (4-byte elements)
    float* ws     = (float*)d_ws;
    float* XL     = ws;                        // [N,128]
    float* XR     = ws + 6400000;              // [N,128]
    float* LIN    = ws + 12800000;             // [N,128]
    int*   counts = (int*)(ws + 19200000);     // [N]  (also scatter cursor)
    int*   rowptr = counts + 50000;            // [N+1]
    int*   csr    = rowptr + 50001;            // [E_TOT]
    // layer-2 per-node vectors staged in the d_out TAIL (overwritten last by
    // copy_eidx; fused2 reads them before that — stream-ordered, safe)
    float* XL2    = out + 100000;
    float* XR2    = out + 200000;
    float* LIN2   = out + 300000;

    // --- Layer-1 GEMM (LDS-tiled, conflict-free staging) ---
    {
        dim3 grid((N_NODES + TRR - 1) / TRR, 6);
        gemm1_kernel<<<grid, 256, 0, stream>>>(x, Wl1, Wr1, Wlin1, XL, XR, LIN);
    }

    // --- CSR build ---
    hipMemsetAsync(counts, 0, N_NODES * sizeof(int), stream);
    hist_kernel<<<(E_TOT + 255) / 256, 256, 0, stream>>>(eidx, counts);
    scan_kernel<<<1, 1024, 0, stream>>>(counts, rowptr, counts);
    scatter_kernel<<<(E_TOT + 255) / 256, 256, 0, stream>>>(eidx, counts, csr);

    // --- Fused layer-1 GAT + layer-2 projections (wave per node) ---
    {
        const int blocks = (N_NODES * 64 + 255) / 256;
        fused1_kernel<<<blocks, 256, 0, stream>>>(XL, XR, LIN, rowptr, csr,
                                                  att1, b1, blin1,
                                                  Wl2, Wr2, Wlin2,
                                                  XL2, XR2, LIN2);
    }

    // --- Fused layer-2 GAT + log_softmax (16 lanes per node) ---
    {
        const int blocks = (N_NODES * 16 + 255) / 256;
        fused2_kernel<<<blocks, 256, 0, stream>>>(XL2, XR2, LIN2, rowptr, csr,
                                                  att2, b2, blin2, out);
    }

    // --- edge_index copy LAST (overwrites the out-tail scratch) ---
    {
        const int blocks = (2 * E_RAW + 255) / 256;
        copy_eidx_kernel<<<blocks, 256, 0, stream>>>(eidx, out + (size_t)N_NODES * 2);
    }
}

// Round 11
// 352.633 us; speedup vs baseline: 8.0500x; 1.1132x over previous
//
#include <hip/hip_runtime.h>
#include <math.h>

#define N_NODES 50000
#define F_IN 128
#define E_RAW 800000
#define E_TOT (E_RAW + N_NODES)   // self-loops appended
#define NEG_SLOPE 0.2f
#define NPART 196                 // ceil(50000/256)

// ---------------------------------------------------------------------------
// Kernel 1: LDS-tiled fused GEMM  X[N,128] @ [Wl1|Wr1|Wlin1] -> XL, XR, LIN
// Round-11: k-blocked b128 LDS reads. XS[row][36] (stride 36 floats, 16B
// aligned, pad ≡ 4 mod 32 banks): b128 STORES are conflict-free (quarter-wave
// covers 2 whole rows -> 64 dwords over 32 banks); compute reads 4-k blocks:
// per thread 8 broadcast b128 X + 4 b128 W feed 128 FMAs (DS 144cy < VALU
// 256cy per wave -> VALU-bound). Round-10 version did 8 scalar b32 per k
// (DS-throughput bound, 86µs).
// ---------------------------------------------------------------------------
#define TRR 128      // tile rows
#define TCC 64       // tile cols
#define KBB 32       // k chunk
#define XST 36       // XS row stride in floats (16B-aligned, bank-spread pad)

__global__ __launch_bounds__(256, 4) void gemm1_kernel(
    const float* __restrict__ x,
    const float* __restrict__ Wl, const float* __restrict__ Wr,
    const float* __restrict__ Wlin,
    float* __restrict__ XL, float* __restrict__ XR, float* __restrict__ LIN)
{
    __shared__ float XS[TRR][XST];   // [row][k]  18.4 KB
    __shared__ float WS[KBB][TCC];   // [k][col]   8 KB

    const int t  = threadIdx.x;
    const int tx = t & 15;           // col group: cols tx*4 .. tx*4+3
    const int ty = t >> 4;           // row group: rows ty*8 .. ty*8+7

    const int r0   = blockIdx.x * TRR;
    const int half = blockIdx.y & 1;
    const int mat  = blockIdx.y >> 1;     // 0=Wl 1=Wr 2=Wlin
    const int cs0  = half * 64;

    const float* Wsel = (mat == 0) ? Wl : (mat == 1) ? Wr : Wlin;
    float*       Osel = (mat == 0) ? XL : (mat == 1) ? XR : LIN;

    const int sx_k4  = t & 7;    // float4 slot within the 32-k chunk
    const int sx_row = t >> 3;   // row 0..31 (+32*i)

    float acc[8][4];
    #pragma unroll
    for (int r = 0; r < 8; ++r)
        #pragma unroll
        for (int c = 0; c < 4; ++c) acc[r][c] = 0.f;

    for (int kc = 0; kc < 128; kc += KBB) {
        // stage X chunk: coalesced global float4, b128 LDS store (conflict-free)
        #pragma unroll
        for (int i = 0; i < 4; ++i) {
            const int row = sx_row + i * 32;
            const int gr  = r0 + row;
            float4 v = (gr < N_NODES)
                ? *(const float4*)(x + (size_t)gr * 128 + kc + sx_k4 * 4)
                : make_float4(0.f, 0.f, 0.f, 0.f);
            *(float4*)&XS[row][sx_k4 * 4] = v;
        }
        // stage W chunk
        #pragma unroll
        for (int i = 0; i < 2; ++i) {
            const int wk = (t >> 4) + i * 16;
            float4 wv = *(const float4*)(Wsel + (size_t)(kc + wk) * 128 + cs0 + tx * 4);
            *(float4*)&WS[wk][tx * 4] = wv;
        }
        __syncthreads();

        // compute in 4-k blocks: 8 broadcast b128 X + 4 b128 W -> 128 FMA
        #pragma unroll 1
        for (int kb = 0; kb < 8; ++kb) {
            const float4 wv0 = *(const float4*)&WS[kb * 4 + 0][tx * 4];
            const float4 wv1 = *(const float4*)&WS[kb * 4 + 1][tx * 4];
            const float4 wv2 = *(const float4*)&WS[kb * 4 + 2][tx * 4];
            const float4 wv3 = *(const float4*)&WS[kb * 4 + 3][tx * 4];
            #pragma unroll
            for (int r = 0; r < 8; ++r) {
                const float4 xq = *(const float4*)&XS[ty * 8 + r][kb * 4];
                acc[r][0] = fmaf(xq.x, wv0.x, acc[r][0]);
                acc[r][1] = fmaf(xq.x, wv0.y, acc[r][1]);
                acc[r][2] = fmaf(xq.x, wv0.z, acc[r][2]);
                acc[r][3] = fmaf(xq.x, wv0.w, acc[r][3]);
                acc[r][0] = fmaf(xq.y, wv1.x, acc[r][0]);
                acc[r][1] = fmaf(xq.y, wv1.y, acc[r][1]);
                acc[r][2] = fmaf(xq.y, wv1.z, acc[r][2]);
                acc[r][3] = fmaf(xq.y, wv1.w, acc[r][3]);
                acc[r][0] = fmaf(xq.z, wv2.x, acc[r][0]);
                acc[r][1] = fmaf(xq.z, wv2.y, acc[r][1]);
                acc[r][2] = fmaf(xq.z, wv2.z, acc[r][2]);
                acc[r][3] = fmaf(xq.z, wv2.w, acc[r][3]);
                acc[r][0] = fmaf(xq.w, wv3.x, acc[r][0]);
                acc[r][1] = fmaf(xq.w, wv3.y, acc[r][1]);
                acc[r][2] = fmaf(xq.w, wv3.z, acc[r][2]);
                acc[r][3] = fmaf(xq.w, wv3.w, acc[r][3]);
            }
        }
        __syncthreads();
    }

    #pragma unroll
    for (int r = 0; r < 8; ++r) {
        const int grow = r0 + ty * 8 + r;
        if (grow < N_NODES) {
            float4 o = make_float4(acc[r][0], acc[r][1], acc[r][2], acc[r][3]);
            *(float4*)(Osel + (size_t)grow * 128 + cs0 + tx * 4) = o;
        }
    }
}

// ---------------------------------------------------------------------------
// CSR build: histogram, PARALLEL 3-kernel scan, scatter
// ---------------------------------------------------------------------------
__global__ __launch_bounds__(256) void hist_kernel(
    const int* __restrict__ eidx, int* __restrict__ counts)
{
    const int e = blockIdx.x * blockDim.x + threadIdx.x;
    if (e >= E_TOT) return;
    const int d = (e < E_RAW) ? eidx[E_RAW + e] : e - E_RAW;
    atomicAdd(&counts[d], 1);
}

// A: per-block (256-elem) sums
__global__ __launch_bounds__(256) void scan_partial_kernel(
    const int* __restrict__ counts, int* __restrict__ part)
{
    const int i = blockIdx.x * 256 + threadIdx.x;
    int v = (i < N_NODES) ? counts[i] : 0;
    #pragma unroll
    for (int off = 32; off > 0; off >>= 1) v += __shfl_xor(v, off);
    __shared__ int ws[4];
    if ((threadIdx.x & 63) == 0) ws[threadIdx.x >> 6] = v;
    __syncthreads();
    if (threadIdx.x == 0) part[blockIdx.x] = ws[0] + ws[1] + ws[2] + ws[3];
}

// B: exclusive scan of the 196 partials, one block
__global__ __launch_bounds__(256) void scan_part_kernel(int* __restrict__ part)
{
    const int t = threadIdx.x, lane = t & 63, w = t >> 6;
    int v = (t < NPART) ? part[t] : 0;
    const int orig = v;
    #pragma unroll
    for (int off = 1; off < 64; off <<= 1) {
        int u = __shfl_up(v, off);
        if (lane >= off) v += u;
    }
    __shared__ int ws[4];
    if (lane == 63) ws[w] = v;
    __syncthreads();
    int add = 0;
    for (int j = 0; j < w; ++j) add += ws[j];
    if (t < NPART) part[t] = add + v - orig;   // exclusive
}

// C: apply block offsets -> rowptr + cursor
__global__ __launch_bounds__(256) void scan_apply_kernel(
    const int* __restrict__ counts, const int* __restrict__ part,
    int* __restrict__ rowptr, int* __restrict__ cursor)
{
    const int i = blockIdx.x * 256 + threadIdx.x;
    const int t = threadIdx.x, lane = t & 63, w = t >> 6;
    int v = (i < N_NODES) ? counts[i] : 0;
    const int orig = v;
    #pragma unroll
    for (int off = 1; off < 64; off <<= 1) {
        int u = __shfl_up(v, off);
        if (lane >= off) v += u;
    }
    __shared__ int ws[4];
    if (lane == 63) ws[w] = v;
    __syncthreads();
    int add = part[blockIdx.x];
    for (int j = 0; j < w; ++j) add += ws[j];
    if (i < N_NODES) {
        const int e = add + v - orig;
        rowptr[i] = e;
        cursor[i] = e;
    }
    if (i == 0) rowptr[N_NODES] = E_TOT;
}

__global__ __launch_bounds__(256) void scatter_kernel(
    const int* __restrict__ eidx, int* __restrict__ cursor, int* __restrict__ csr_src)
{
    const int e = blockIdx.x * blockDim.x + threadIdx.x;
    if (e >= E_TOT) return;
    int s, d;
    if (e < E_RAW) { s = eidx[e]; d = eidx[E_RAW + e]; }
    else           { s = d = e - E_RAW; }
    const int pos = atomicAdd(&cursor[d], 1);
    csr_src[pos] = s;
}

// ---------------------------------------------------------------------------
// Fused layer-1 GAT + layer-2 projections (round-10 verified): one wave per
// dst node, 4 edges in flight; epilogue computes h (relu) and the three W2
// dots in-register; H never materialized.
// ---------------------------------------------------------------------------
__global__ __launch_bounds__(256) void fused1_kernel(
    const float* __restrict__ xl, const float* __restrict__ xr,
    const float* __restrict__ lin,
    const int* __restrict__ rowptr, const int* __restrict__ csr_src,
    const float* __restrict__ att, const float* __restrict__ b1,
    const float* __restrict__ blin1,
    const float* __restrict__ Wl2, const float* __restrict__ Wr2,
    const float* __restrict__ Wlin2,
    float* __restrict__ XL2, float* __restrict__ XR2, float* __restrict__ LIN2)
{
    const int gid  = blockIdx.x * blockDim.x + threadIdx.x;
    const int d    = gid >> 6;
    const int lane = gid & 63;
    if (d >= N_NODES) return;
    const int grp = lane >> 4;      // edge slot 0..3
    const int sub = lane & 15;      // dim group

    const int r0 = rowptr[d], r1 = rowptr[d + 1];

    const float4 xr0 = *(const float4*)(xr + (size_t)d * 128 + sub * 8);
    const float4 xr1 = *(const float4*)(xr + (size_t)d * 128 + sub * 8 + 4);
    const float4 at0 = *(const float4*)(att + sub * 8);
    const float4 at1 = *(const float4*)(att + sub * 8 + 4);

    float num[8] = {0.f,0.f,0.f,0.f,0.f,0.f,0.f,0.f};
    float den = 0.f;

    for (int j = r0; j < r1; j += 4) {
        const int e  = j + grp;
        const int ee = (e < E_TOT) ? e : (E_TOT - 1);
        const int s  = csr_src[ee];
        const float4 a0 = *(const float4*)(xl + (size_t)s * 128 + sub * 8);
        const float4 a1 = *(const float4*)(xl + (size_t)s * 128 + sub * 8 + 4);

        float m, v = 0.f;
        m = a0.x + xr0.x; m = m > 0.f ? m : NEG_SLOPE * m; v = fmaf(m, at0.x, v);
        m = a0.y + xr0.y; m = m > 0.f ? m : NEG_SLOPE * m; v = fmaf(m, at0.y, v);
        m = a0.z + xr0.z; m = m > 0.f ? m : NEG_SLOPE * m; v = fmaf(m, at0.z, v);
        m = a0.w + xr0.w; m = m > 0.f ? m : NEG_SLOPE * m; v = fmaf(m, at0.w, v);
        m = a1.x + xr1.x; m = m > 0.f ? m : NEG_SLOPE * m; v = fmaf(m, at1.x, v);
        m = a1.y + xr1.y; m = m > 0.f ? m : NEG_SLOPE * m; v = fmaf(m, at1.y, v);
        m = a1.z + xr1.z; m = m > 0.f ? m : NEG_SLOPE * m; v = fmaf(m, at1.z, v);
        m = a1.w + xr1.w; m = m > 0.f ? m : NEG_SLOPE * m; v = fmaf(m, at1.w, v);

        v += __shfl_xor(v, 1);
        v += __shfl_xor(v, 2);
        v += __shfl_xor(v, 4);
        v += __shfl_xor(v, 8);

        const float ex = (e < r1) ? __expf(v) : 0.f;
        den += ex;
        num[0] = fmaf(ex, a0.x, num[0]);
        num[1] = fmaf(ex, a0.y, num[1]);
        num[2] = fmaf(ex, a0.z, num[2]);
        num[3] = fmaf(ex, a0.w, num[3]);
        num[4] = fmaf(ex, a1.x, num[4]);
        num[5] = fmaf(ex, a1.y, num[5]);
        num[6] = fmaf(ex, a1.z, num[6]);
        num[7] = fmaf(ex, a1.w, num[7]);
    }

    // combine the 4 edge groups -> every lane holds full num/den
    den += __shfl_xor(den, 16);
    den += __shfl_xor(den, 32);
    #pragma unroll
    for (int i = 0; i < 8; ++i) {
        num[i] += __shfl_xor(num[i], 16);
        num[i] += __shfl_xor(num[i], 32);
    }

    // epilogue: h dims (relu) on all lanes, then W2 dots + 16-lane reduce
    const float inv = 1.f / den;
    const float4 l0  = *(const float4*)(lin   + (size_t)d * 128 + sub * 8);
    const float4 l1  = *(const float4*)(lin   + (size_t)d * 128 + sub * 8 + 4);
    const float4 bb0 = *(const float4*)(b1    + sub * 8);
    const float4 bb1 = *(const float4*)(b1    + sub * 8 + 4);
    const float4 bl0 = *(const float4*)(blin1 + sub * 8);
    const float4 bl1 = *(const float4*)(blin1 + sub * 8 + 4);
    float h0 = fmaf(num[0], inv, bb0.x) + l0.x + bl0.x;
    float h1 = fmaf(num[1], inv, bb0.y) + l0.y + bl0.y;
    float h2 = fmaf(num[2], inv, bb0.z) + l0.z + bl0.z;
    float h3 = fmaf(num[3], inv, bb0.w) + l0.w + bl0.w;
    float h4 = fmaf(num[4], inv, bb1.x) + l1.x + bl1.x;
    float h5 = fmaf(num[5], inv, bb1.y) + l1.y + bl1.y;
    float h6 = fmaf(num[6], inv, bb1.z) + l1.z + bl1.z;
    float h7 = fmaf(num[7], inv, bb1.w) + l1.w + bl1.w;
    h0 = h0 > 0.f ? h0 : 0.f;  h1 = h1 > 0.f ? h1 : 0.f;
    h2 = h2 > 0.f ? h2 : 0.f;  h3 = h3 > 0.f ? h3 : 0.f;
    h4 = h4 > 0.f ? h4 : 0.f;  h5 = h5 > 0.f ? h5 : 0.f;
    h6 = h6 > 0.f ? h6 : 0.f;  h7 = h7 > 0.f ? h7 : 0.f;

    float pl0, pl1, pr0, pr1, pn0, pn1;
    {
        const float4 a = ((const float4*)Wl2)[sub*4+0];
        const float4 b = ((const float4*)Wl2)[sub*4+1];
        const float4 c = ((const float4*)Wl2)[sub*4+2];
        const float4 e4= ((const float4*)Wl2)[sub*4+3];
        pl0 = h0*a.x + h1*a.z + h2*b.x + h3*b.z + h4*c.x + h5*c.z + h6*e4.x + h7*e4.z;
        pl1 = h0*a.y + h1*a.w + h2*b.y + h3*b.w + h4*c.y + h5*c.w + h6*e4.y + h7*e4.w;
    }
    {
        const float4 a = ((const float4*)Wr2)[sub*4+0];
        const float4 b = ((const float4*)Wr2)[sub*4+1];
        const float4 c = ((const float4*)Wr2)[sub*4+2];
        const float4 e4= ((const float4*)Wr2)[sub*4+3];
        pr0 = h0*a.x + h1*a.z + h2*b.x + h3*b.z + h4*c.x + h5*c.z + h6*e4.x + h7*e4.z;
        pr1 = h0*a.y + h1*a.w + h2*b.y + h3*b.w + h4*c.y + h5*c.w + h6*e4.y + h7*e4.w;
    }
    {
        const float4 a = ((const float4*)Wlin2)[sub*4+0];
        const float4 b = ((const float4*)Wlin2)[sub*4+1];
        const float4 c = ((const float4*)Wlin2)[sub*4+2];
        const float4 e4= ((const float4*)Wlin2)[sub*4+3];
        pn0 = h0*a.x + h1*a.z + h2*b.x + h3*b.z + h4*c.x + h5*c.z + h6*e4.x + h7*e4.z;
        pn1 = h0*a.y + h1*a.w + h2*b.y + h3*b.w + h4*c.y + h5*c.w + h6*e4.y + h7*e4.w;
    }
    #pragma unroll
    for (int off = 1; off < 16; off <<= 1) {
        pl0 += __shfl_xor(pl0, off); pl1 += __shfl_xor(pl1, off);
        pr0 += __shfl_xor(pr0, off); pr1 += __shfl_xor(pr1, off);
        pn0 += __shfl_xor(pn0, off); pn1 += __shfl_xor(pn1, off);
    }
    if (lane == 0) {
        XL2[d*2+0]  = pl0; XL2[d*2+1]  = pl1;
        XR2[d*2+0]  = pr0; XR2[d*2+1]  = pr1;
        LIN2[d*2+0] = pn0; LIN2[d*2+1] = pn1;
    }
}

// ---------------------------------------------------------------------------
// Fused layer-2 GAT + bias + skip + log_softmax: 16 lanes per node
// ---------------------------------------------------------------------------
__global__ __launch_bounds__(256) void fused2_kernel(
    const float* __restrict__ XL2, const float* __restrict__ XR2,
    const float* __restrict__ LIN2,
    const int* __restrict__ rowptr, const int* __restrict__ csr_src,
    const float* __restrict__ att2, const float* __restrict__ b2,
    const float* __restrict__ blin2,
    float* __restrict__ out)
{
    const int gid = blockIdx.x * blockDim.x + threadIdx.x;
    const int d   = gid >> 4;
    const int l16 = gid & 15;
    if (d >= N_NODES) return;

    const int r0 = rowptr[d], r1 = rowptr[d + 1];
    const float2 xrv = *(const float2*)(XR2 + (size_t)d * 2);
    const float a0 = att2[0], a1 = att2[1];

    float num0 = 0.f, num1 = 0.f, den = 0.f;
    for (int j = r0 + l16; j < r1; j += 16) {
        const int s = csr_src[j];
        const float2 l = *(const float2*)(XL2 + (size_t)s * 2);
        float m0 = l.x + xrv.x, m1 = l.y + xrv.y;
        m0 = m0 > 0.f ? m0 : NEG_SLOPE * m0;
        m1 = m1 > 0.f ? m1 : NEG_SLOPE * m1;
        const float ex = __expf(fmaf(m0, a0, m1 * a1));
        den += ex;
        num0 = fmaf(ex, l.x, num0);
        num1 = fmaf(ex, l.y, num1);
    }
    #pragma unroll
    for (int off = 1; off < 16; off <<= 1) {
        den  += __shfl_xor(den,  off);
        num0 += __shfl_xor(num0, off);
        num1 += __shfl_xor(num1, off);
    }
    if (l16 == 0) {
        const float inv = 1.f / den;
        const float o0 = num0 * inv + b2[0] + LIN2[d*2+0] + blin2[0];
        const float o1 = num1 * inv + b2[1] + LIN2[d*2+1] + blin2[1];
        const float mx  = fmaxf(o0, o1);
        const float lse = mx + logf(__expf(o0 - mx) + __expf(o1 - mx));
        out[d*2+0] = o0 - lse;
        out[d*2+1] = o1 - lse;
    }
}

// ---------------------------------------------------------------------------
// copy edge_index (int32) -> d_out tail as float32 (runs LAST: overwrites the
// XL2/XR2/LIN2 scratch staged in the out tail)
// ---------------------------------------------------------------------------
__global__ __launch_bounds__(256) void copy_eidx_kernel(
    const int* __restrict__ eidx, float* __restrict__ out)
{
    const int i = blockIdx.x * blockDim.x + threadIdx.x;
    if (i >= 2 * E_RAW) return;
    out[i] = (float)eidx[i];
}

// ---------------------------------------------------------------------------
extern "C" void kernel_launch(void* const* d_in, const int* in_sizes, int n_in,
                              void* d_out, int out_size, void* d_ws, size_t ws_size,
                              hipStream_t stream)
{
    const float* x      = (const float*)d_in[0];
    const int*   eidx   = (const int*)  d_in[1];
    const float* Wl1    = (const float*)d_in[2];
    const float* Wr1    = (const float*)d_in[3];
    const float* att1   = (const float*)d_in[4];
    const float* b1     = (const float*)d_in[5];
    const float* Wlin1  = (const float*)d_in[6];
    const float* blin1  = (const float*)d_in[7];
    const float* Wl2    = (const float*)d_in[8];
    const float* Wr2    = (const float*)d_in[9];
    const float* att2   = (const float*)d_in[10];
    const float* b2     = (const float*)d_in[11];
    const float* Wlin2  = (const float*)d_in[12];
    const float* blin2  = (const float*)d_in[13];

    float* out = (float*)d_out;

    // workspace layout (4-byte elements)
    float* ws     = (float*)d_ws;
    float* XL     = ws;                        // [N,128]
    float* XR     = ws + 6400000;              // [N,128]
    float* LIN    = ws + 12800000;             // [N,128]
    int*   counts = (int*)(ws + 19200000);     // [N]
    int*   rowptr = counts + 50000;            // [N+1]
    int*   csr    = rowptr + 50001;            // [E_TOT]
    int*   part   = csr + E_TOT;               // [NPART]
    int*   cursor = part + NPART;              // [N]
    // layer-2 per-node vectors staged in the d_out TAIL (overwritten last by
    // copy_eidx; fused2 reads them before that — stream-ordered, safe)
    float* XL2    = out + 100000;
    float* XR2    = out + 200000;
    float* LIN2   = out + 300000;

    // --- Layer-1 GEMM ---
    {
        dim3 grid((N_NODES + TRR - 1) / TRR, 6);
        gemm1_kernel<<<grid, 256, 0, stream>>>(x, Wl1, Wr1, Wlin1, XL, XR, LIN);
    }

    // --- CSR build (parallel scan) ---
    hipMemsetAsync(counts, 0, N_NODES * sizeof(int), stream);
    hist_kernel<<<(E_TOT + 255) / 256, 256, 0, stream>>>(eidx, counts);
    scan_partial_kernel<<<NPART, 256, 0, stream>>>(counts, part);
    scan_part_kernel<<<1, 256, 0, stream>>>(part);
    scan_apply_kernel<<<NPART, 256, 0, stream>>>(counts, part, rowptr, cursor);
    scatter_kernel<<<(E_TOT + 255) / 256, 256, 0, stream>>>(eidx, cursor, csr);

    // --- Fused layer-1 GAT + layer-2 projections (wave per node) ---
    {
        const int blocks = (N_NODES * 64 + 255) / 256;
        fused1_kernel<<<blocks, 256, 0, stream>>>(XL, XR, LIN, rowptr, csr,
                                                  att1, b1, blin1,
                                                  Wl2, Wr2, Wlin2,
                                                  XL2, XR2, LIN2);
    }

    // --- Fused layer-2 GAT + log_softmax (16 lanes per node) ---
    {
        const int blocks = (N_NODES * 16 + 255) / 256;
        fused2_kernel<<<blocks, 256, 0, stream>>>(XL2, XR2, LIN2, rowptr, csr,
                                                  att2, b2, blin2, out);
    }

    // --- edge_index copy LAST (overwrites the out-tail scratch) ---
    {
        const int blocks = (2 * E_RAW + 255) / 256;
        copy_eidx_kernel<<<blocks, 256, 0, stream>>>(eidx, out + (size_t)N_NODES * 2);
    }
}

// Round 15
// 348.356 us; speedup vs baseline: 8.1488x; 1.0123x over previous
//
#include <hip/hip_runtime.h>
#include <math.h>

#define N_NODES 50000
#define F_IN 128
#define E_RAW 800000
#define E_TOT (E_RAW + N_NODES)   // self-loops appended
#define NEG_SLOPE 0.2f
#define NPART 196                 // ceil(50000/256)

// ---------------------------------------------------------------------------
// Kernel 1: LDS-tiled fused GEMM  X[N,128] @ [Wl1|Wr1|Wlin1] -> XL, XR, LIN
// (round-11 verified: k-blocked b128 reads, stride-36 X tile, 0 conflicts)
// ---------------------------------------------------------------------------
#define TRR 128      // tile rows
#define TCC 64       // tile cols
#define KBB 32       // k chunk
#define XST 36       // XS row stride in floats (16B-aligned, bank-spread pad)

__global__ __launch_bounds__(256, 4) void gemm1_kernel(
    const float* __restrict__ x,
    const float* __restrict__ Wl, const float* __restrict__ Wr,
    const float* __restrict__ Wlin,
    float* __restrict__ XL, float* __restrict__ XR, float* __restrict__ LIN)
{
    __shared__ float XS[TRR][XST];   // [row][k]  18.4 KB
    __shared__ float WS[KBB][TCC];   // [k][col]   8 KB

    const int t  = threadIdx.x;
    const int tx = t & 15;
    const int ty = t >> 4;

    const int r0   = blockIdx.x * TRR;
    const int half = blockIdx.y & 1;
    const int mat  = blockIdx.y >> 1;     // 0=Wl 1=Wr 2=Wlin
    const int cs0  = half * 64;

    const float* Wsel = (mat == 0) ? Wl : (mat == 1) ? Wr : Wlin;
    float*       Osel = (mat == 0) ? XL : (mat == 1) ? XR : LIN;

    const int sx_k4  = t & 7;
    const int sx_row = t >> 3;

    float acc[8][4];
    #pragma unroll
    for (int r = 0; r < 8; ++r)
        #pragma unroll
        for (int c = 0; c < 4; ++c) acc[r][c] = 0.f;

    for (int kc = 0; kc < 128; kc += KBB) {
        #pragma unroll
        for (int i = 0; i < 4; ++i) {
            const int row = sx_row + i * 32;
            const int gr  = r0 + row;
            float4 v = (gr < N_NODES)
                ? *(const float4*)(x + (size_t)gr * 128 + kc + sx_k4 * 4)
                : make_float4(0.f, 0.f, 0.f, 0.f);
            *(float4*)&XS[row][sx_k4 * 4] = v;
        }
        #pragma unroll
        for (int i = 0; i < 2; ++i) {
            const int wk = (t >> 4) + i * 16;
            float4 wv = *(const float4*)(Wsel + (size_t)(kc + wk) * 128 + cs0 + tx * 4);
            *(float4*)&WS[wk][tx * 4] = wv;
        }
        __syncthreads();

        #pragma unroll 1
        for (int kb = 0; kb < 8; ++kb) {
            const float4 wv0 = *(const float4*)&WS[kb * 4 + 0][tx * 4];
            const float4 wv1 = *(const float4*)&WS[kb * 4 + 1][tx * 4];
            const float4 wv2 = *(const float4*)&WS[kb * 4 + 2][tx * 4];
            const float4 wv3 = *(const float4*)&WS[kb * 4 + 3][tx * 4];
            #pragma unroll
            for (int r = 0; r < 8; ++r) {
                const float4 xq = *(const float4*)&XS[ty * 8 + r][kb * 4];
                acc[r][0] = fmaf(xq.x, wv0.x, acc[r][0]);
                acc[r][1] = fmaf(xq.x, wv0.y, acc[r][1]);
                acc[r][2] = fmaf(xq.x, wv0.z, acc[r][2]);
                acc[r][3] = fmaf(xq.x, wv0.w, acc[r][3]);
                acc[r][0] = fmaf(xq.y, wv1.x, acc[r][0]);
                acc[r][1] = fmaf(xq.y, wv1.y, acc[r][1]);
                acc[r][2] = fmaf(xq.y, wv1.z, acc[r][2]);
                acc[r][3] = fmaf(xq.y, wv1.w, acc[r][3]);
                acc[r][0] = fmaf(xq.z, wv2.x, acc[r][0]);
                acc[r][1] = fmaf(xq.z, wv2.y, acc[r][1]);
                acc[r][2] = fmaf(xq.z, wv2.z, acc[r][2]);
                acc[r][3] = fmaf(xq.z, wv2.w, acc[r][3]);
                acc[r][0] = fmaf(xq.w, wv3.x, acc[r][0]);
                acc[r][1] = fmaf(xq.w, wv3.y, acc[r][1]);
                acc[r][2] = fmaf(xq.w, wv3.z, acc[r][2]);
                acc[r][3] = fmaf(xq.w, wv3.w, acc[r][3]);
            }
        }
        __syncthreads();
    }

    #pragma unroll
    for (int r = 0; r < 8; ++r) {
        const int grow = r0 + ty * 8 + r;
        if (grow < N_NODES) {
            float4 o = make_float4(acc[r][0], acc[r][1], acc[r][2], acc[r][3]);
            *(float4*)(Osel + (size_t)grow * 128 + cs0 + tx * 4) = o;
        }
    }
}

// ---------------------------------------------------------------------------
// CSR build: histogram, 2-kernel parallel scan, scatter
// ---------------------------------------------------------------------------
__global__ __launch_bounds__(256) void hist_kernel(
    const int* __restrict__ eidx, int* __restrict__ counts)
{
    const int e = blockIdx.x * blockDim.x + threadIdx.x;
    if (e >= E_TOT) return;
    const int d = (e < E_RAW) ? eidx[E_RAW + e] : e - E_RAW;
    atomicAdd(&counts[d], 1);
}

// A: per-block (256-elem) RAW sums
__global__ __launch_bounds__(256) void scan_partial_kernel(
    const int* __restrict__ counts, int* __restrict__ part)
{
    const int i = blockIdx.x * 256 + threadIdx.x;
    int v = (i < N_NODES) ? counts[i] : 0;
    #pragma unroll
    for (int off = 32; off > 0; off >>= 1) v += __shfl_xor(v, off);
    __shared__ int ws[4];
    if ((threadIdx.x & 63) == 0) ws[threadIdx.x >> 6] = v;
    __syncthreads();
    if (threadIdx.x == 0) part[blockIdx.x] = ws[0] + ws[1] + ws[2] + ws[3];
}

// B: each block computes its own offset from the raw partials (read-only),
// then the local exclusive scan -> rowptr + cursor. (merged r11's B+C)
__global__ __launch_bounds__(256) void scan_apply_kernel(
    const int* __restrict__ counts, const int* __restrict__ part,
    int* __restrict__ rowptr, int* __restrict__ cursor)
{
    __shared__ int smem[NPART];
    __shared__ int ws[4];
    const int t = threadIdx.x, lane = t & 63, w = t >> 6;
    if (t < NPART) smem[t] = part[t];
    __syncthreads();

    int add = 0;
    for (int jj = 0; jj < blockIdx.x; ++jj) add += smem[jj];  // uniform broadcast loop

    const int i = blockIdx.x * 256 + t;
    int v = (i < N_NODES) ? counts[i] : 0;
    const int orig = v;
    #pragma unroll
    for (int off = 1; off < 64; off <<= 1) {
        int u = __shfl_up(v, off);
        if (lane >= off) v += u;
    }
    if (lane == 63) ws[w] = v;
    __syncthreads();
    for (int jj = 0; jj < w; ++jj) add += ws[jj];
    if (i < N_NODES) {
        const int e = add + v - orig;
        rowptr[i] = e;
        cursor[i] = e;
    }
    if (i == 0) rowptr[N_NODES] = E_TOT;
}

__global__ __launch_bounds__(256) void scatter_kernel(
    const int* __restrict__ eidx, int* __restrict__ cursor, int* __restrict__ csr_src)
{
    const int e = blockIdx.x * blockDim.x + threadIdx.x;
    if (e >= E_TOT) return;
    int s, d;
    if (e < E_RAW) { s = eidx[e]; d = eidx[E_RAW + e]; }
    else           { s = d = e - E_RAW; }
    const int pos = atomicAdd(&cursor[d], 1);
    csr_src[pos] = s;
}

// ---------------------------------------------------------------------------
// Fused layer-1 GAT + layer-2 projections, 2-DEEP SOFTWARE PIPELINE:
// indices prefetched 2 batches ahead, gather data 1 batch ahead, so compute
// of batch j overlaps batch j+1's 512B gather and batch j+2's index load.
// ---------------------------------------------------------------------------
__global__ __launch_bounds__(256) void fused1_kernel(
    const float* __restrict__ xl, const float* __restrict__ xr,
    const float* __restrict__ lin,
    const int* __restrict__ rowptr, const int* __restrict__ csr_src,
    const float* __restrict__ att, const float* __restrict__ b1,
    const float* __restrict__ blin1,
    const float* __restrict__ Wl2, const float* __restrict__ Wr2,
    const float* __restrict__ Wlin2,
    float* __restrict__ XL2, float* __restrict__ XR2, float* __restrict__ LIN2)
{
    const int gid  = blockIdx.x * blockDim.x + threadIdx.x;
    const int d    = gid >> 6;
    const int lane = gid & 63;
    if (d >= N_NODES) return;
    const int grp = lane >> 4;      // edge slot 0..3
    const int sub = lane & 15;      // dim group

    const int r0 = rowptr[d], r1 = rowptr[d + 1];

    const float4 xr0 = *(const float4*)(xr + (size_t)d * 128 + sub * 8);
    const float4 xr1 = *(const float4*)(xr + (size_t)d * 128 + sub * 8 + 4);
    const float4 at0 = *(const float4*)(att + sub * 8);
    const float4 at1 = *(const float4*)(att + sub * 8 + 4);

    float num[8] = {0.f,0.f,0.f,0.f,0.f,0.f,0.f,0.f};
    float den = 0.f;

    // prologue: index + data for batch 0, index for batch 1
    int i_cur = r0 + grp;           if (i_cur >= E_TOT) i_cur = E_TOT - 1;
    int i_nx  = r0 + 4 + grp;       if (i_nx  >= E_TOT) i_nx  = E_TOT - 1;
    int s_nxt = csr_src[i_nx];
    {
        const int s0 = csr_src[i_cur];
        // fallthrough into loop with a0/a1 preloaded
        float4 p0 = *(const float4*)(xl + (size_t)s0 * 128 + sub * 8);
        float4 p1 = *(const float4*)(xl + (size_t)s0 * 128 + sub * 8 + 4);

        for (int j = r0; j < r1; j += 4) {
            // issue next batch's data load (index already resident)
            const float4 b0 = *(const float4*)(xl + (size_t)s_nxt * 128 + sub * 8);
            const float4 b1 = *(const float4*)(xl + (size_t)s_nxt * 128 + sub * 8 + 4);
            // issue index load 2 batches ahead
            int i_fut = j + 8 + grp; if (i_fut >= E_TOT) i_fut = E_TOT - 1;
            const int s_fut = csr_src[i_fut];

            // compute on current batch (p0/p1), edge e = j + grp
            const int e = j + grp;
            float m, v = 0.f;
            m = p0.x + xr0.x; m = m > 0.f ? m : NEG_SLOPE * m; v = fmaf(m, at0.x, v);
            m = p0.y + xr0.y; m = m > 0.f ? m : NEG_SLOPE * m; v = fmaf(m, at0.y, v);
            m = p0.z + xr0.z; m = m > 0.f ? m : NEG_SLOPE * m; v = fmaf(m, at0.z, v);
            m = p0.w + xr0.w; m = m > 0.f ? m : NEG_SLOPE * m; v = fmaf(m, at0.w, v);
            m = p1.x + xr1.x; m = m > 0.f ? m : NEG_SLOPE * m; v = fmaf(m, at1.x, v);
            m = p1.y + xr1.y; m = m > 0.f ? m : NEG_SLOPE * m; v = fmaf(m, at1.y, v);
            m = p1.z + xr1.z; m = m > 0.f ? m : NEG_SLOPE * m; v = fmaf(m, at1.z, v);
            m = p1.w + xr1.w; m = m > 0.f ? m : NEG_SLOPE * m; v = fmaf(m, at1.w, v);

            v += __shfl_xor(v, 1);
            v += __shfl_xor(v, 2);
            v += __shfl_xor(v, 4);
            v += __shfl_xor(v, 8);

            const float ex = (e < r1) ? __expf(v) : 0.f;
            den += ex;
            num[0] = fmaf(ex, p0.x, num[0]);
            num[1] = fmaf(ex, p0.y, num[1]);
            num[2] = fmaf(ex, p0.z, num[2]);
            num[3] = fmaf(ex, p0.w, num[3]);
            num[4] = fmaf(ex, p1.x, num[4]);
            num[5] = fmaf(ex, p1.y, num[5]);
            num[6] = fmaf(ex, p1.z, num[6]);
            num[7] = fmaf(ex, p1.w, num[7]);

            // rotate pipeline
            p0 = b0; p1 = b1; s_nxt = s_fut;
        }
    }

    // combine the 4 edge groups -> every lane holds full num/den
    den += __shfl_xor(den, 16);
    den += __shfl_xor(den, 32);
    #pragma unroll
    for (int i = 0; i < 8; ++i) {
        num[i] += __shfl_xor(num[i], 16);
        num[i] += __shfl_xor(num[i], 32);
    }

    // epilogue: h dims (relu) on all lanes, then W2 dots + 16-lane reduce
    const float inv = 1.f / den;
    const float4 l0  = *(const float4*)(lin   + (size_t)d * 128 + sub * 8);
    const float4 l1  = *(const float4*)(lin   + (size_t)d * 128 + sub * 8 + 4);
    const float4 bb0 = *(const float4*)(b1    + sub * 8);
    const float4 bb1 = *(const float4*)(b1    + sub * 8 + 4);
    const float4 bl0 = *(const float4*)(blin1 + sub * 8);
    const float4 bl1 = *(const float4*)(blin1 + sub * 8 + 4);
    float h0 = fmaf(num[0], inv, bb0.x) + l0.x + bl0.x;
    float h1 = fmaf(num[1], inv, bb0.y) + l0.y + bl0.y;
    float h2 = fmaf(num[2], inv, bb0.z) + l0.z + bl0.z;
    float h3 = fmaf(num[3], inv, bb0.w) + l0.w + bl0.w;
    float h4 = fmaf(num[4], inv, bb1.x) + l1.x + bl1.x;
    float h5 = fmaf(num[5], inv, bb1.y) + l1.y + bl1.y;
    float h6 = fmaf(num[6], inv, bb1.z) + l1.z + bl1.z;
    float h7 = fmaf(num[7], inv, bb1.w) + l1.w + bl1.w;
    h0 = h0 > 0.f ? h0 : 0.f;  h1 = h1 > 0.f ? h1 : 0.f;
    h2 = h2 > 0.f ? h2 : 0.f;  h3 = h3 > 0.f ? h3 : 0.f;
    h4 = h4 > 0.f ? h4 : 0.f;  h5 = h5 > 0.f ? h5 : 0.f;
    h6 = h6 > 0.f ? h6 : 0.f;  h7 = h7 > 0.f ? h7 : 0.f;

    float pl0, pl1, pr0, pr1, pn0, pn1;
    {
        const float4 a = ((const float4*)Wl2)[sub*4+0];
        const float4 b = ((const float4*)Wl2)[sub*4+1];
        const float4 c = ((const float4*)Wl2)[sub*4+2];
        const float4 e4= ((const float4*)Wl2)[sub*4+3];
        pl0 = h0*a.x + h1*a.z + h2*b.x + h3*b.z + h4*c.x + h5*c.z + h6*e4.x + h7*e4.z;
        pl1 = h0*a.y + h1*a.w + h2*b.y + h3*b.w + h4*c.y + h5*c.w + h6*e4.y + h7*e4.w;
    }
    {
        const float4 a = ((const float4*)Wr2)[sub*4+0];
        const float4 b = ((const float4*)Wr2)[sub*4+1];
        const float4 c = ((const float4*)Wr2)[sub*4+2];
        const float4 e4= ((const float4*)Wr2)[sub*4+3];
        pr0 = h0*a.x + h1*a.z + h2*b.x + h3*b.z + h4*c.x + h5*c.z + h6*e4.x + h7*e4.z;
        pr1 = h0*a.y + h1*a.w + h2*b.y + h3*b.w + h4*c.y + h5*c.w + h6*e4.y + h7*e4.w;
    }
    {
        const float4 a = ((const float4*)Wlin2)[sub*4+0];
        const float4 b = ((const float4*)Wlin2)[sub*4+1];
        const float4 c = ((const float4*)Wlin2)[sub*4+2];
        const float4 e4= ((const float4*)Wlin2)[sub*4+3];
        pn0 = h0*a.x + h1*a.z + h2*b.x + h3*b.z + h4*c.x + h5*c.z + h6*e4.x + h7*e4.z;
        pn1 = h0*a.y + h1*a.w + h2*b.y + h3*b.w + h4*c.y + h5*c.w + h6*e4.y + h7*e4.w;
    }
    #pragma unroll
    for (int off = 1; off < 16; off <<= 1) {
        pl0 += __shfl_xor(pl0, off); pl1 += __shfl_xor(pl1, off);
        pr0 += __shfl_xor(pr0, off); pr1 += __shfl_xor(pr1, off);
        pn0 += __shfl_xor(pn0, off); pn1 += __shfl_xor(pn1, off);
    }
    if (lane == 0) {
        XL2[d*2+0]  = pl0; XL2[d*2+1]  = pl1;
        XR2[d*2+0]  = pr0; XR2[d*2+1]  = pr1;
        LIN2[d*2+0] = pn0; LIN2[d*2+1] = pn1;
    }
}

// ---------------------------------------------------------------------------
// Fused layer-2 GAT + bias + skip + log_softmax: 16 lanes per node
// ---------------------------------------------------------------------------
__global__ __launch_bounds__(256) void fused2_kernel(
    const float* __restrict__ XL2, const float* __restrict__ XR2,
    const float* __restrict__ LIN2,
    const int* __restrict__ rowptr, const int* __restrict__ csr_src,
    const float* __restrict__ att2, const float* __restrict__ b2,
    const float* __restrict__ blin2,
    float* __restrict__ out)
{
    const int gid = blockIdx.x * blockDim.x + threadIdx.x;
    const int d   = gid >> 4;
    const int l16 = gid & 15;
    if (d >= N_NODES) return;

    const int r0 = rowptr[d], r1 = rowptr[d + 1];
    const float2 xrv = *(const float2*)(XR2 + (size_t)d * 2);
    const float a0 = att2[0], a1 = att2[1];

    float num0 = 0.f, num1 = 0.f, den = 0.f;
    for (int j = r0 + l16; j < r1; j += 16) {
        const int s = csr_src[j];
        const float2 l = *(const float2*)(XL2 + (size_t)s * 2);
        float m0 = l.x + xrv.x, m1 = l.y + xrv.y;
        m0 = m0 > 0.f ? m0 : NEG_SLOPE * m0;
        m1 = m1 > 0.f ? m1 : NEG_SLOPE * m1;
        const float ex = __expf(fmaf(m0, a0, m1 * a1));
        den += ex;
        num0 = fmaf(ex, l.x, num0);
        num1 = fmaf(ex, l.y, num1);
    }
    #pragma unroll
    for (int off = 1; off < 16; off <<= 1) {
        den  += __shfl_xor(den,  off);
        num0 += __shfl_xor(num0, off);
        num1 += __shfl_xor(num1, off);
    }
    if (l16 == 0) {
        const float inv = 1.f / den;
        const float o0 = num0 * inv + b2[0] + LIN2[d*2+0] + blin2[0];
        const float o1 = num1 * inv + b2[1] + LIN2[d*2+1] + blin2[1];
        const float mx  = fmaxf(o0, o1);
        const float lse = mx + logf(__expf(o0 - mx) + __expf(o1 - mx));
        out[d*2+0] = o0 - lse;
        out[d*2+1] = o1 - lse;
    }
}

// ---------------------------------------------------------------------------
// copy edge_index (int32) -> d_out tail as float32 (runs LAST: overwrites the
// XL2/XR2/LIN2 scratch staged in the out tail)
// ---------------------------------------------------------------------------
__global__ __launch_bounds__(256) void copy_eidx_kernel(
    const int* __restrict__ eidx, float* __restrict__ out)
{
    const int i = blockIdx.x * blockDim.x + threadIdx.x;
    if (i >= 2 * E_RAW) return;
    out[i] = (float)eidx[i];
}

// ---------------------------------------------------------------------------
extern "C" void kernel_launch(void* const* d_in, const int* in_sizes, int n_in,
                              void* d_out, int out_size, void* d_ws, size_t ws_size,
                              hipStream_t stream)
{
    const float* x      = (const float*)d_in[0];
    const int*   eidx   = (const int*)  d_in[1];
    const float* Wl1    = (const float*)d_in[2];
    const float* Wr1    = (const float*)d_in[3];
    const float* att1   = (const float*)d_in[4];
    const float* b1     = (const float*)d_in[5];
    const float* Wlin1  = (const float*)d_in[6];
    const float* blin1  = (const float*)d_in[7];
    const float* Wl2    = (const float*)d_in[8];
    const float* Wr2    = (const float*)d_in[9];
    const float* att2   = (const float*)d_in[10];
    const float* b2     = (const float*)d_in[11];
    const float* Wlin2  = (const float*)d_in[12];
    const float* blin2  = (const float*)d_in[13];

    float* out = (float*)d_out;

    // workspace layout (4-byte elements)
    float* ws     = (float*)d_ws;
    float* XL     = ws;                        // [N,128]
    float* XR     = ws + 6400000;              // [N,128]
    float* LIN    = ws + 12800000;             // [N,128]
    int*   counts = (int*)(ws + 19200000);     // [N]
    int*   rowptr = counts + 50000;            // [N+1]
    int*   csr    = rowptr + 50001;            // [E_TOT]
    int*   part   = csr + E_TOT;               // [NPART]
    int*   cursor = part + NPART;              // [N]
    // layer-2 per-node vectors staged in the d_out TAIL (overwritten last by
    // copy_eidx; fused2 reads them before that — stream-ordered, safe)
    float* XL2    = out + 100000;
    float* XR2    = out + 200000;
    float* LIN2   = out + 300000;

    // --- Layer-1 GEMM ---
    {
        dim3 grid((N_NODES + TRR - 1) / TRR, 6);
        gemm1_kernel<<<grid, 256, 0, stream>>>(x, Wl1, Wr1, Wlin1, XL, XR, LIN);
    }

    // --- CSR build (2-kernel parallel scan) ---
    hipMemsetAsync(counts, 0, N_NODES * sizeof(int), stream);
    hist_kernel<<<(E_TOT + 255) / 256, 256, 0, stream>>>(eidx, counts);
    scan_partial_kernel<<<NPART, 256, 0, stream>>>(counts, part);
    scan_apply_kernel<<<NPART, 256, 0, stream>>>(counts, part, rowptr, cursor);
    scatter_kernel<<<(E_TOT + 255) / 256, 256, 0, stream>>>(eidx, cursor, csr);

    // --- Fused layer-1 GAT + layer-2 projections (wave per node, pipelined) ---
    {
        const int blocks = (N_NODES * 64 + 255) / 256;
        fused1_kernel<<<blocks, 256, 0, stream>>>(XL, XR, LIN, rowptr, csr,
                                                  att1, b1, blin1,
                                                  Wl2, Wr2, Wlin2,
                                                  XL2, XR2, LIN2);
    }

    // --- Fused layer-2 GAT + log_softmax (16 lanes per node) ---
    {
        const int blocks = (N_NODES * 16 + 255) / 256;
        fused2_kernel<<<blocks, 256, 0, stream>>>(XL2, XR2, LIN2, rowptr, csr,
                                                  att2, b2, blin2, out);
    }

    // --- edge_index copy LAST (overwrites the out-tail scratch) ---
    {
        const int blocks = (2 * E_RAW + 255) / 256;
        copy_eidx_kernel<<<blocks, 256, 0, stream>>>(eidx, out + (size_t)N_NODES * 2);
    }
}